// Round 13
// baseline (186.122 us; speedup 1.0000x reference)
//
#include <hip/hip_runtime.h>
#include <math.h>

typedef __attribute__((ext_vector_type(4))) float f4;
typedef __attribute__((ext_vector_type(16))) float f16v;
typedef __attribute__((ext_vector_type(8))) short s8;      // 8 x bf16 fragment
typedef __attribute__((ext_vector_type(4))) unsigned short u16x4;
typedef unsigned short u16;
typedef unsigned int u32;

constexpr int kB = 16, kC = 512, kL = 1024, kNH = 8, kG = 32;
constexpr float kEps = 1e-5f;
constexpr float kQScale = 0.18033688011112042f;  // 0.125 * log2(e)

// fp32 -> bf16 RNE (scalar)
__device__ __forceinline__ u16 f2bf(float f) {
    union { float f; unsigned u; } c; c.f = f;
    unsigned u = c.u;
    return (u16)((u + 0x7fffu + ((u >> 16) & 1u)) >> 16);
}
__device__ __forceinline__ float bf2f(u16 v) {
    union { u32 u; float f; } c; c.u = (u32)v << 16; return c.f;
}
// packed 2x f32 -> 2x bf16 in one instr (lo in [15:0], hi in [31:16])
__device__ __forceinline__ u32 pkbf(float lo, float hi) {
    u32 r;
    asm("v_cvt_pk_bf16_f32 %0, %1, %2" : "=v"(r) : "v"(lo), "v"(hi));
    return r;
}
// raw hardware 2^x — single v_exp_f32, no OCML guard sequence
__device__ __forceinline__ float exp2hw(float x) {
    float r;
    asm("v_exp_f32 %0, %1" : "=v"(r) : "v"(x));
    return r;
}

// async global->LDS, 16B per lane. LDS dest = wave-uniform base + lane*16.
__device__ __forceinline__ void gload_lds16(const void* g, void* l) {
    __builtin_amdgcn_global_load_lds(
        (const __attribute__((address_space(1))) void*)g,
        (__attribute__((address_space(3))) void*)l, 16, 0, 0);
}

// ---------------------------------------------------------------------------
// Fused prep kernel (independent jobs, one launch):
//   blocks    0..1023 : wq|wk|wv|wo fp32 -> bf16 contiguous (wqkvB | woB)
//   blocks 1024..1087 : conv_w [c][e] -> transposed bf16 [e][c]
//   blocks 1088..1471 : folded bias b' = Wqkv@conv_b + b_qkv (fp32)
//   blocks 1472..1983 : GroupNorm stats per (b,g)
// ---------------------------------------------------------------------------
__global__ __launch_bounds__(256)
void prep1_kernel(const float* __restrict__ wq, const float* __restrict__ wk,
                  const float* __restrict__ wv, const float* __restrict__ wo,
                  const float* __restrict__ cw, const float* __restrict__ bq,
                  const float* __restrict__ bk, const float* __restrict__ bv,
                  const float* __restrict__ convb, const float* __restrict__ x,
                  u16* __restrict__ dst, u16* __restrict__ dstT,
                  float* __restrict__ outb, float2* __restrict__ stats)
{
    __shared__ float t[64][65];
    const int tid = threadIdx.x;
    const int bid = blockIdx.x;
    if (bid < 1024) {
        int idx = bid * 256 + tid;                    // float4 index
        int m = idx >> 16;
        int r = idx & 65535;
        const float* srcs[4] = {wq, wk, wv, wo};
        float4 v = ((const float4*)srcs[m])[r];
        u16x4 o; o.x = f2bf(v.x); o.y = f2bf(v.y); o.z = f2bf(v.z); o.w = f2bf(v.w);
        ((u16x4*)dst)[idx] = o;
    } else if (bid < 1088) {
        int b2 = bid - 1024;                          // 0..63
        const int c0 = (b2 >> 3) * 64, e0 = (b2 & 7) * 64;
        #pragma unroll
        for (int it = 0; it < 4; ++it) {
            int c = it * 16 + (tid >> 4);
            int e4 = (tid & 15) * 4;
            float4 v = *(const float4*)&cw[(size_t)(c0 + c) * kC + e0 + e4];
            t[c][e4 + 0] = v.x; t[c][e4 + 1] = v.y;
            t[c][e4 + 2] = v.z; t[c][e4 + 3] = v.w;
        }
        __syncthreads();
        #pragma unroll
        for (int it = 0; it < 4; ++it) {
            int e = it * 16 + (tid >> 4);
            int c4 = (tid & 15) * 4;
            u16x4 o;
            o.x = f2bf(t[c4 + 0][e]); o.y = f2bf(t[c4 + 1][e]);
            o.z = f2bf(t[c4 + 2][e]); o.w = f2bf(t[c4 + 3][e]);
            *(u16x4*)&dstT[(size_t)(e0 + e) * kC + c0 + c4] = o;
        }
    } else if (bid < 1472) {
        const int o = (bid - 1088) * 4 + (tid >> 6);  // 0..1535
        const int lane = tid & 63;
        const float* w; const float* borig; int m2;
        if (o < 512)       { w = wq; borig = bq; m2 = o; }
        else if (o < 1024) { w = wk; borig = bk; m2 = o - 512; }
        else               { w = wv; borig = bv; m2 = o - 1024; }
        const float* wr = w + (size_t)m2 * kC + lane * 8;
        const float* cb = convb + lane * 8;
        float4 a0 = *(const float4*)wr,  a1 = *(const float4*)(wr + 4);
        float4 b0 = *(const float4*)cb,  b1 = *(const float4*)(cb + 4);
        float s = a0.x * b0.x + a0.y * b0.y + a0.z * b0.z + a0.w * b0.w
                + a1.x * b1.x + a1.y * b1.y + a1.z * b1.z + a1.w * b1.w;
        #pragma unroll
        for (int off = 32; off > 0; off >>= 1) s += __shfl_down(s, off);
        if (lane == 0) outb[o] = s + borig[m2];
    } else {
        const int bg = bid - 1472;                    // 0..511
        const float4* p = (const float4*)(x + (size_t)bg * (16 * kL));
        float s = 0.f, ss = 0.f;
        for (int i = tid; i < (16 * kL) / 4; i += 256) {
            float4 v = p[i];
            s  += v.x + v.y + v.z + v.w;
            ss += v.x * v.x + v.y * v.y + v.z * v.z + v.w * v.w;
        }
        #pragma unroll
        for (int off = 32; off > 0; off >>= 1) {
            s  += __shfl_down(s, off);
            ss += __shfl_down(ss, off);
        }
        __shared__ float rs[4], rss[4];
        if ((tid & 63) == 0) { rs[tid >> 6] = s; rss[tid >> 6] = ss; }
        __syncthreads();
        if (tid == 0) {
            float S = rs[0] + rs[1] + rs[2] + rs[3];
            float SS = rss[0] + rss[1] + rss[2] + rss[3];
            const float inv_n = 1.f / (float)(16 * kL);
            float mean = S * inv_n;
            float var  = SS * inv_n - mean * mean;
            stats[bg] = make_float2(mean, rsqrtf(var + kEps));
        }
    }
}

// ---------------------------------------------------------------------------
// GN apply + transpose + bf16 cast:  x [B][C][L] fp32 -> xt [B][L][C] bf16
// ---------------------------------------------------------------------------
__global__ __launch_bounds__(256)
void gn_t_kernel(const float* __restrict__ x, const float2* __restrict__ stats,
                 const float* __restrict__ gnw, const float* __restrict__ gnb,
                 u16* __restrict__ xt)
{
    __shared__ float t[64][65];
    const int tid = threadIdx.x;
    const int b = blockIdx.z, c0 = blockIdx.y * 64, l0 = blockIdx.x * 64;
    const float* xb = x + ((size_t)(b * kC + c0)) * kL + l0;
    #pragma unroll
    for (int it = 0; it < 4; ++it) {
        int c = it * 16 + (tid >> 4);
        int l4i = (tid & 15) * 4;
        float4 v = *(const float4*)&xb[(size_t)c * kL + l4i];
        float2 st = stats[b * kG + ((c0 + c) >> 4)];
        float a  = st.y * gnw[c0 + c];
        float bb = gnb[c0 + c] - st.x * a;
        t[c][l4i + 0] = v.x * a + bb;
        t[c][l4i + 1] = v.y * a + bb;
        t[c][l4i + 2] = v.z * a + bb;
        t[c][l4i + 3] = v.w * a + bb;
    }
    __syncthreads();
    u16* ob = xt + ((size_t)(b * kL + l0)) * kC + c0;
    #pragma unroll
    for (int it = 0; it < 4; ++it) {
        int l = it * 16 + (tid >> 4);
        int c4 = (tid & 15) * 4;
        u16x4 o;
        o.x = f2bf(t[c4 + 0][l]); o.y = f2bf(t[c4 + 1][l]);
        o.z = f2bf(t[c4 + 2][l]); o.w = f2bf(t[c4 + 3][l]);
        *(u16x4*)&ob[(size_t)l * kC + c4] = o;
    }
}

// ---------------------------------------------------------------------------
// bf16 MFMA GEMM: D[m][n] = sum_k W[m][k]*X[b][n][k]
// BK=32, SINGLE barrier per K-step: {vmcnt(0); barrier; stage(t+1); compute}.
// Hoisted addressing, flat XCD-grouped grid for EPI 1/2.
// EPI: 1 = QKV route (q,k -> [L][C]; v -> [C][L]); bias0 = folded 1536-vec
//      2 = fp32 [C][L] + bias + residual (final)
//      3 = bf16 [m][n] row-major, no bias (weight-fold product, 3D grid)
// ---------------------------------------------------------------------------
template <int EPI>
__global__ __launch_bounds__(256, 4)
void gemm_mfma(const u16* __restrict__ W, const u16* __restrict__ X,
               const float* __restrict__ bias0,
               u16* __restrict__ o0, u16* __restrict__ o1, u16* __restrict__ o2,
               const float* __restrict__ resid, float* __restrict__ outf)
{
    __shared__ short lds[2][2][128 * 32];   // 32 KB total
    const int tid = threadIdx.x, lane = tid & 63, w = tid >> 6;
    const int l15 = lane & 15, l4 = lane >> 4;

    int bxi, byi, bb;
    if constexpr (EPI == 3) {
        bxi = blockIdx.x; byi = blockIdx.y; bb = blockIdx.z;
    } else {
        // flat grid: f%8 = XCD residue -> batches {2r, 2r+1}
        int f = blockIdx.x;
        int xcd = f & 7, i = f >> 3;
        bb = 2 * xcd + (i & 1);
        int j = i >> 1;
        byi = j >> 3; bxi = j & 7;
    }
    const int bm = byi * 128, bn = bxi * 128;
    const u16* Ag = W + (size_t)bm * kC;
    const u16* Bg = X + ((size_t)bb * kL + bn) * kC;
    const int wm = (w >> 1) * 64, wn = (w & 1) * 64;

    f4 acc[4][4] = {};

    // --- hoisted staging constants: 512 16B-units per matrix, 2/thread ---
    size_t ago[2];
    int ldd[2];
    #pragma unroll
    for (int i = 0; i < 2; ++i) {
        int unit = i * 256 + tid;
        int row = unit >> 2, pos = unit & 3;
        ago[i] = (size_t)row * kC + ((pos ^ (row & 3)) << 3);
        ldd[i] = unit * 8;
    }
    auto stage = [&](int kt, int bi) {
        #pragma unroll
        for (int i = 0; i < 2; ++i) {
            gload_lds16(Ag + ago[i] + kt, &lds[bi][0][ldd[i]]);
            gload_lds16(Bg + ago[i] + kt, &lds[bi][1][ldd[i]]);
        }
    };

    // --- hoisted fragment LDS offsets (rows of 32 shorts, 4 slots, XOR row&3)
    int aoff[4], boff[4];
    #pragma unroll
    for (int f = 0; f < 4; ++f) {
        int ra = wm + f * 16 + l15;
        aoff[f] = ra * 32 + ((l4 ^ (ra & 3)) << 3);
        int rb = wn + f * 16 + l15;
        boff[f] = rb * 32 + ((l4 ^ (rb & 3)) << 3);
    }

    stage(0, 0);

    for (int t = 0; t < 16; ++t) {
        const int cur = t & 1;
        // own loads (tile t) done; barrier => everyone's done => buf[cur]
        // fully populated AND all reads of buf[cur^1] (iter t-1) retired.
        asm volatile("s_waitcnt vmcnt(0)" ::: "memory");
        __builtin_amdgcn_s_barrier();
        if (t < 15) stage((t + 1) * 32, cur ^ 1);

        const short* La = &lds[cur][0][0];
        const short* Lb = &lds[cur][1][0];
        s8 af[4], bfr[4];
        #pragma unroll
        for (int f = 0; f < 4; ++f) {
            af[f]  = *(const s8*)(La + aoff[f]);
            bfr[f] = *(const s8*)(Lb + boff[f]);
        }
        __builtin_amdgcn_s_setprio(1);
        #pragma unroll
        for (int fi = 0; fi < 4; ++fi)
            #pragma unroll
            for (int fj = 0; fj < 4; ++fj)
                acc[fi][fj] = __builtin_amdgcn_mfma_f32_16x16x32_bf16(
                    af[fi], bfr[fj], acc[fi][fj], 0, 0, 0);
        __builtin_amdgcn_s_setprio(0);
    }

    #pragma unroll
    for (int fi = 0; fi < 4; ++fi) {
        const int mb = bm + wm + fi * 16 + 4 * l4;
        if constexpr (EPI == 2) {
            #pragma unroll
            for (int fj = 0; fj < 4; ++fj) {
                const int n = bn + wn + fj * 16 + l15;
                #pragma unroll
                for (int r = 0; r < 4; ++r) {
                    size_t idx = ((size_t)(bb * kC + mb + r)) * kL + n;
                    outf[idx] = acc[fi][fj][r] + bias0[mb + r] + resid[idx];
                }
            }
        } else if constexpr (EPI == 3) {
            #pragma unroll
            for (int fj = 0; fj < 4; ++fj) {
                const int n = bn + wn + fj * 16 + l15;
                #pragma unroll
                for (int r = 0; r < 4; ++r)
                    o0[(size_t)(mb + r) * kC + n] = f2bf(acc[fi][fj][r]);
            }
        } else {  // EPI == 1: QKV routing, bias0 = folded 1536-vector
            if (mb < 1024) {
                u16* dst = (mb < 512) ? o0 : o1;
                const int m2 = mb & 511;
                float bs[4] = {bias0[mb], bias0[mb + 1], bias0[mb + 2], bias0[mb + 3]};
                #pragma unroll
                for (int fj = 0; fj < 4; ++fj) {
                    const int n = bn + wn + fj * 16 + l15;
                    u16x4 pk;
                    #pragma unroll
                    for (int r = 0; r < 4; ++r) pk[r] = f2bf(acc[fi][fj][r] + bs[r]);
                    *(u16x4*)&dst[((size_t)(bb * kL + n)) * kC + m2] = pk;
                }
            } else {
                const int m2 = mb - 1024;   // V -> transposed [C][L]
                #pragma unroll
                for (int fj = 0; fj < 4; ++fj) {
                    const int n = bn + wn + fj * 16 + l15;
                    #pragma unroll
                    for (int r = 0; r < 4; ++r)
                        o2[((size_t)(bb * kC + m2 + r)) * kL + n] =
                            f2bf(acc[fi][fj][r] + bias0[mb + r]);
                }
            }
        }
    }
}

// ---------------------------------------------------------------------------
// Flash attention v11b: KVBLK=128 (2 KV 64-tiles per barrier), lsum on VALU,
// raw v_exp_f32, single-barrier pipeline, unnormalized softmax, zero-shuffle
// PV via K-row permutation (swap b2,b3; within-64-window so both halves ok).
// FIX vs v11: V staging decomposition. K rows are j-pairs (j 0..127 valid),
// but V rows are d-pairs (d 0..63 only): units 512..1023 must map to
// half=1 (j-offset 64), same d 0..63 — NOT d 64..127 (that read the next
// head's V). half = row>>5; d = (row&31)*2+(s>>3); src = d*kL + half*64+sub8.
// LDS side unchanged (swizzle key row&15 is half-invariant, 32 = 0 mod 16).
// ---------------------------------------------------------------------------
__global__ __launch_bounds__(512, 4)
void attn_mfma(const u16* __restrict__ q, const u16* __restrict__ k,
               const u16* __restrict__ vt, u16* __restrict__ o)
{
    __shared__ short ldsK[2][64 * 128];   // [buf][j-pair row(128 j)][128] swz
    __shared__ short ldsV[2][64 * 128];   // [buf][half|d-pair row][128] swz

    const int tid = threadIdx.x, lane = tid & 63, w = tid >> 6;   // w 0..7
    const int l31 = lane & 31, h5 = lane >> 5;

    // XCD grouping: all 4 q2-tiles of one (b,h) -> same flat%8 residue
    const int flat = blockIdx.x;                  // 512 blocks
    const int bh = (flat & 7) * 16 + (flat >> 5); // 0..127
    const int qt2 = (flat >> 3) & 3;
    const int b = bh >> 3, h = bh & 7;

    const size_t qrow0 = (size_t)b * kL + qt2 * 256 + w * 32;
    const u16* Qh = q + qrow0 * kC + h * 64;
    const u16* Kb = k + ((size_t)b * kL) * kC + h * 64;
    const u16* Vb = vt + ((size_t)b * kC + h * 64) * kL;

    s8 qf[4];
    #pragma unroll
    for (int ks = 0; ks < 4; ++ks) {
        s8 raw = *(const s8*)(Qh + (size_t)l31 * kC + ks * 16 + h5 * 8);
        #pragma unroll
        for (int e = 0; e < 8; e += 2) {
            u32 pk = pkbf(bf2f((u16)raw[e]) * kQScale,
                          bf2f((u16)raw[e + 1]) * kQScale);
            qf[ks][e]     = (short)(pk & 0xffff);
            qf[ks][e + 1] = (short)(pk >> 16);
        }
    }

    f16v oacc0 = {}, oacc1 = {};   // O^T rows d, col q = l31
    float ls = 0.f;                // in-lane partial softmax denominator

    // --- staging: 1024 16B-units per 128-j tile-pair, 2 K + 2 V per thread ---
    size_t kgo[2], vgo[2];
    int ldd[2];
    #pragma unroll
    for (int i = 0; i < 2; ++i) {
        int u_ = i * 512 + tid;
        int row = u_ >> 4, pos = u_ & 15;         // LDS pair-row 0..63
        int s = pos ^ (row & 15);
        int sub8 = (s & 7) << 3;
        // K: row is a j-pair index over the full 128-j tile
        int jd = row * 2 + (s >> 3);              // j 0..127
        int jda = (jd & 0x73) | ((jd & 4) << 1) | ((jd & 8) >> 1); // swap b2,b3
        kgo[i] = (size_t)jda * kC + sub8;
        // V: row 0..31 = half 0 (j 0..63), row 32..63 = half 1 (j 64..127);
        // within a half, rows are d-pairs with d 0..63.
        int half = row >> 5, rr = row & 31;
        int d = rr * 2 + (s >> 3);                // 0..63
        vgo[i] = (size_t)d * kL + half * 64 + sub8;
        ldd[i] = u_ * 8;
    }
    auto stage = [&](int jt2, int bi) {
        #pragma unroll
        for (int i = 0; i < 2; ++i) {
            gload_lds16(Kb + kgo[i] + (size_t)jt2 * (128 * kC), &ldsK[bi][ldd[i]]);
            gload_lds16(Vb + vgo[i] + jt2 * 128,                &ldsV[bi][ldd[i]]);
        }
    };

    const int sbase = (l31 & 1) << 3;
    const int rlo = l31 >> 1;
    int loff[4];
    #pragma unroll
    for (int ks = 0; ks < 4; ++ks) {
        int s_ = sbase | (2 * ks + h5);
        loff[ks] = rlo * 128 + ((s_ ^ (rlo & 15)) << 3);
    }

    stage(0, 0);

    for (int t = 0; t < 8; ++t) {
        const int cur = t & 1;
        asm volatile("s_waitcnt vmcnt(0)" ::: "memory");
        __builtin_amdgcn_s_barrier();
        if (t < 7) stage(t + 1, cur ^ 1);

        #pragma unroll
        for (int half = 0; half < 2; ++half) {
            const short* Kl = &ldsK[cur][half * 4096];   // 32 pair-rows/half
            const short* Vl = &ldsV[cur][half * 4096];

            // S = K Q  (score-row s holds key pi(s); key-order invariant)
            f16v sf0 = {}, sf1 = {};
            __builtin_amdgcn_s_setprio(1);
            #pragma unroll
            for (int ks = 0; ks < 4; ++ks) {
                s8 kf0 = *(const s8*)(Kl + loff[ks]);
                s8 kf1 = *(const s8*)(Kl + loff[ks] + 2048);
                sf0 = __builtin_amdgcn_mfma_f32_32x32x16_bf16(kf0, qf[ks], sf0, 0, 0, 0);
                sf1 = __builtin_amdgcn_mfma_f32_32x32x16_bf16(kf1, qf[ks], sf1, 0, 0, 0);
            }
            __builtin_amdgcn_s_setprio(0);

            // P = exp2(S) — raw v_exp_f32; no max subtraction (bounded inputs)
            #pragma unroll
            for (int r = 0; r < 16; ++r) {
                sf0[r] = exp2hw(sf0[r]);
                sf1[r] = exp2hw(sf1[r]);
            }

            // lsum on the VALU pipe: 4-way ILP tree over this lane's 32 p's
            {
                float t0 = 0.f, t1 = 0.f, t2 = 0.f, t3 = 0.f;
                #pragma unroll
                for (int r = 0; r < 16; r += 4) {
                    t0 += sf0[r];     t1 += sf0[r + 1];
                    t2 += sf0[r + 2]; t3 += sf0[r + 3];
                }
                #pragma unroll
                for (int r = 0; r < 16; r += 4) {
                    t0 += sf1[r];     t1 += sf1[r + 1];
                    t2 += sf1[r + 2]; t3 += sf1[r + 3];
                }
                ls += (t0 + t1) + (t2 + t3);
            }

            // PV B-fragments: window ks = lane's own regs r0..r0+7 in order
            s8 pf[4];
            #pragma unroll
            for (int ks = 0; ks < 4; ++ks) {
                const f16v& pv = (ks < 2) ? sf0 : sf1;
                const int r0 = 8 * (ks & 1);
                union { u32 wd[4]; s8 v; } u;
                u.wd[0] = pkbf(pv[r0 + 0], pv[r0 + 1]);
                u.wd[1] = pkbf(pv[r0 + 2], pv[r0 + 3]);
                u.wd[2] = pkbf(pv[r0 + 4], pv[r0 + 5]);
                u.wd[3] = pkbf(pv[r0 + 6], pv[r0 + 7]);
                pf[ks] = u.v;
            }

            // O^T += V^T P
            __builtin_amdgcn_s_setprio(1);
            #pragma unroll
            for (int ks = 0; ks < 4; ++ks) {
                s8 vf0 = *(const s8*)(Vl + loff[ks]);
                s8 vf1 = *(const s8*)(Vl + loff[ks] + 2048);
                oacc0 = __builtin_amdgcn_mfma_f32_32x32x16_bf16(vf0, pf[ks], oacc0, 0, 0, 0);
                oacc1 = __builtin_amdgcn_mfma_f32_32x32x16_bf16(vf1, pf[ks], oacc1, 0, 0, 0);
            }
            __builtin_amdgcn_s_setprio(0);
        }
    }

    // denominator: own 32-sum (x2 halves) + partner half-lane's sums
    const float inv = 1.0f / (ls + __shfl_xor(ls, 32));
    u16* orow = o + (qrow0 + l31) * kC + h * 64;
    #pragma unroll
    for (int db = 0; db < 2; ++db) {
        const f16v& oa = db ? oacc1 : oacc0;
        #pragma unroll
        for (int g = 0; g < 4; ++g) {
            int d0 = db * 32 + g * 8 + 4 * h5;
            u32 w0 = pkbf(oa[g * 4 + 0] * inv, oa[g * 4 + 1] * inv);
            u32 w1 = pkbf(oa[g * 4 + 2] * inv, oa[g * 4 + 3] * inv);
            u16x4 pk;
            pk[0] = (u16)(w0 & 0xffff); pk[1] = (u16)(w0 >> 16);
            pk[2] = (u16)(w1 & 0xffff); pk[3] = (u16)(w1 >> 16);
            *(u16x4*)&orow[d0] = pk;
        }
    }
}

// ---------------------------------------------------------------------------
extern "C" void kernel_launch(void* const* d_in, const int* in_sizes, int n_in,
                              void* d_out, int out_size, void* d_ws, size_t ws_size,
                              hipStream_t stream)
{
    const float* x      = (const float*)d_in[0];
    const float* gn_w   = (const float*)d_in[1];
    const float* gn_b   = (const float*)d_in[2];
    const float* conv_w = (const float*)d_in[3];
    const float* conv_b = (const float*)d_in[4];
    const float* wq     = (const float*)d_in[5];
    const float* bq     = (const float*)d_in[6];
    const float* wk     = (const float*)d_in[7];
    const float* bk     = (const float*)d_in[8];
    const float* wv     = (const float*)d_in[9];
    const float* bv     = (const float*)d_in[10];
    const float* wo     = (const float*)d_in[11];
    const float* bo     = (const float*)d_in[12];
    float* out = (float*)d_out;

    char* ws = (char*)d_ws;
    float2* stats = (float2*)ws;                       // 4 KB (8 KB reserved)
    u16* wqkvB  = (u16*)(ws + 8192);                   // 1.5 MB (q|k|v stacked)
    u16* woB    = wqkvB + 786432;                      // 0.5 MB (contiguous after wqkvB)
    u16* convwT = woB + 262144;                        // 0.5 MB
    u16* wqkvF  = convwT + 262144;                     // 1.5 MB (folded weights)
    float* bqkvF = (float*)(wqkvF + 786432);           // 6 KB
    const size_t ACT = (size_t)kB * kL * kC;
    u16* xt  = (u16*)(ws + (6 << 20));
    u16* qb  = xt + ACT;
    u16* kb  = qb + ACT;
    u16* vtb = kb + ACT;
    u16* res = xt;   // xt dead after QKV GEMM; reuse for attention output

    // --- fused prep: weight cvt + conv_w transpose + bias fold + GN stats ---
    prep1_kernel<<<1984, 256, 0, stream>>>(wq, wk, wv, wo, conv_w,
                                           bq, bk, bv, conv_b, x,
                                           wqkvB, convwT, bqkvF, stats);
    // W' = Wqkv @ conv_w   (fold 1x1 conv into QKV projections)
    gemm_mfma<3><<<dim3(4, 12, 1), 256, 0, stream>>>(
        wqkvB, convwT, nullptr, wqkvF, nullptr, nullptr, nullptr, nullptr);
    // GN-normalize + transpose input
    gn_t_kernel<<<dim3(16, 8, kB), 256, 0, stream>>>(x, stats, gn_w, gn_b, xt);

    // q,k,v (v transposed) from normalized input via folded weights (flat grid)
    gemm_mfma<1><<<1536, 256, 0, stream>>>(
        wqkvF, xt, bqkvF, qb, kb, vtb, nullptr, nullptr);
    attn_mfma<<<dim3(512), 512, 0, stream>>>(qb, kb, vtb, res);
    // out = wo @ res + bo + x  (flat grid)
    gemm_mfma<2><<<512, 256, 0, stream>>>(
        woB, res, bo, nullptr, nullptr, nullptr, x, out);
}

// Round 14
// 128.684 us; speedup vs baseline: 1.4463x; 1.4463x over previous
//
#include <hip/hip_runtime.h>
#include <math.h>

typedef __attribute__((ext_vector_type(4))) float f4;
typedef __attribute__((ext_vector_type(16))) float f16v;
typedef __attribute__((ext_vector_type(8))) short s8;      // 8 x bf16 fragment
typedef __attribute__((ext_vector_type(4))) unsigned short u16x4;
typedef unsigned short u16;
typedef unsigned int u32;

constexpr int kB = 16, kC = 512, kL = 1024, kNH = 8, kG = 32;
constexpr float kEps = 1e-5f;
constexpr float kQScale = 0.18033688011112042f;  // 0.125 * log2(e)

// fp32 -> bf16 RNE (scalar)
__device__ __forceinline__ u16 f2bf(float f) {
    union { float f; unsigned u; } c; c.f = f;
    unsigned u = c.u;
    return (u16)((u + 0x7fffu + ((u >> 16) & 1u)) >> 16);
}
__device__ __forceinline__ float bf2f(u16 v) {
    union { u32 u; float f; } c; c.u = (u32)v << 16; return c.f;
}
// packed 2x f32 -> 2x bf16 in one instr (lo in [15:0], hi in [31:16])
__device__ __forceinline__ u32 pkbf(float lo, float hi) {
    u32 r;
    asm("v_cvt_pk_bf16_f32 %0, %1, %2" : "=v"(r) : "v"(lo), "v"(hi));
    return r;
}
// raw hardware 2^x — single v_exp_f32, no OCML guard sequence
__device__ __forceinline__ float exp2hw(float x) {
    float r;
    asm("v_exp_f32 %0, %1" : "=v"(r) : "v"(x));
    return r;
}

// async global->LDS, 16B per lane. LDS dest = wave-uniform base + lane*16.
__device__ __forceinline__ void gload_lds16(const void* g, void* l) {
    __builtin_amdgcn_global_load_lds(
        (const __attribute__((address_space(1))) void*)g,
        (__attribute__((address_space(3))) void*)l, 16, 0, 0);
}

// ---------------------------------------------------------------------------
// Fused prep kernel (independent jobs, one launch):
//   blocks    0..1023 : wq|wk|wv|wo fp32 -> bf16 contiguous (wqkvB | woB)
//   blocks 1024..1087 : conv_w [c][e] -> transposed bf16 [e][c]
//   blocks 1088..1471 : folded bias b' = Wqkv@conv_b + b_qkv (fp32)
//   blocks 1472..1983 : GroupNorm stats per (b,g)
// ---------------------------------------------------------------------------
__global__ __launch_bounds__(256)
void prep1_kernel(const float* __restrict__ wq, const float* __restrict__ wk,
                  const float* __restrict__ wv, const float* __restrict__ wo,
                  const float* __restrict__ cw, const float* __restrict__ bq,
                  const float* __restrict__ bk, const float* __restrict__ bv,
                  const float* __restrict__ convb, const float* __restrict__ x,
                  u16* __restrict__ dst, u16* __restrict__ dstT,
                  float* __restrict__ outb, float2* __restrict__ stats)
{
    __shared__ float t[64][65];
    const int tid = threadIdx.x;
    const int bid = blockIdx.x;
    if (bid < 1024) {
        int idx = bid * 256 + tid;                    // float4 index
        int m = idx >> 16;
        int r = idx & 65535;
        const float* srcs[4] = {wq, wk, wv, wo};
        float4 v = ((const float4*)srcs[m])[r];
        u16x4 o; o.x = f2bf(v.x); o.y = f2bf(v.y); o.z = f2bf(v.z); o.w = f2bf(v.w);
        ((u16x4*)dst)[idx] = o;
    } else if (bid < 1088) {
        int b2 = bid - 1024;                          // 0..63
        const int c0 = (b2 >> 3) * 64, e0 = (b2 & 7) * 64;
        #pragma unroll
        for (int it = 0; it < 4; ++it) {
            int c = it * 16 + (tid >> 4);
            int e4 = (tid & 15) * 4;
            float4 v = *(const float4*)&cw[(size_t)(c0 + c) * kC + e0 + e4];
            t[c][e4 + 0] = v.x; t[c][e4 + 1] = v.y;
            t[c][e4 + 2] = v.z; t[c][e4 + 3] = v.w;
        }
        __syncthreads();
        #pragma unroll
        for (int it = 0; it < 4; ++it) {
            int e = it * 16 + (tid >> 4);
            int c4 = (tid & 15) * 4;
            u16x4 o;
            o.x = f2bf(t[c4 + 0][e]); o.y = f2bf(t[c4 + 1][e]);
            o.z = f2bf(t[c4 + 2][e]); o.w = f2bf(t[c4 + 3][e]);
            *(u16x4*)&dstT[(size_t)(e0 + e) * kC + c0 + c4] = o;
        }
    } else if (bid < 1472) {
        const int o = (bid - 1088) * 4 + (tid >> 6);  // 0..1535
        const int lane = tid & 63;
        const float* w; const float* borig; int m2;
        if (o < 512)       { w = wq; borig = bq; m2 = o; }
        else if (o < 1024) { w = wk; borig = bk; m2 = o - 512; }
        else               { w = wv; borig = bv; m2 = o - 1024; }
        const float* wr = w + (size_t)m2 * kC + lane * 8;
        const float* cb = convb + lane * 8;
        float4 a0 = *(const float4*)wr,  a1 = *(const float4*)(wr + 4);
        float4 b0 = *(const float4*)cb,  b1 = *(const float4*)(cb + 4);
        float s = a0.x * b0.x + a0.y * b0.y + a0.z * b0.z + a0.w * b0.w
                + a1.x * b1.x + a1.y * b1.y + a1.z * b1.z + a1.w * b1.w;
        #pragma unroll
        for (int off = 32; off > 0; off >>= 1) s += __shfl_down(s, off);
        if (lane == 0) outb[o] = s + borig[m2];
    } else {
        const int bg = bid - 1472;                    // 0..511
        const float4* p = (const float4*)(x + (size_t)bg * (16 * kL));
        float s = 0.f, ss = 0.f;
        for (int i = tid; i < (16 * kL) / 4; i += 256) {
            float4 v = p[i];
            s  += v.x + v.y + v.z + v.w;
            ss += v.x * v.x + v.y * v.y + v.z * v.z + v.w * v.w;
        }
        #pragma unroll
        for (int off = 32; off > 0; off >>= 1) {
            s  += __shfl_down(s, off);
            ss += __shfl_down(ss, off);
        }
        __shared__ float rs[4], rss[4];
        if ((tid & 63) == 0) { rs[tid >> 6] = s; rss[tid >> 6] = ss; }
        __syncthreads();
        if (tid == 0) {
            float S = rs[0] + rs[1] + rs[2] + rs[3];
            float SS = rss[0] + rss[1] + rss[2] + rss[3];
            const float inv_n = 1.f / (float)(16 * kL);
            float mean = S * inv_n;
            float var  = SS * inv_n - mean * mean;
            stats[bg] = make_float2(mean, rsqrtf(var + kEps));
        }
    }
}

// ---------------------------------------------------------------------------
// GN apply + transpose + bf16 cast:  x [B][C][L] fp32 -> xt [B][L][C] bf16
// ---------------------------------------------------------------------------
__global__ __launch_bounds__(256)
void gn_t_kernel(const float* __restrict__ x, const float2* __restrict__ stats,
                 const float* __restrict__ gnw, const float* __restrict__ gnb,
                 u16* __restrict__ xt)
{
    __shared__ float t[64][65];
    const int tid = threadIdx.x;
    const int b = blockIdx.z, c0 = blockIdx.y * 64, l0 = blockIdx.x * 64;
    const float* xb = x + ((size_t)(b * kC + c0)) * kL + l0;
    #pragma unroll
    for (int it = 0; it < 4; ++it) {
        int c = it * 16 + (tid >> 4);
        int l4i = (tid & 15) * 4;
        float4 v = *(const float4*)&xb[(size_t)c * kL + l4i];
        float2 st = stats[b * kG + ((c0 + c) >> 4)];
        float a  = st.y * gnw[c0 + c];
        float bb = gnb[c0 + c] - st.x * a;
        t[c][l4i + 0] = v.x * a + bb;
        t[c][l4i + 1] = v.y * a + bb;
        t[c][l4i + 2] = v.z * a + bb;
        t[c][l4i + 3] = v.w * a + bb;
    }
    __syncthreads();
    u16* ob = xt + ((size_t)(b * kL + l0)) * kC + c0;
    #pragma unroll
    for (int it = 0; it < 4; ++it) {
        int l = it * 16 + (tid >> 4);
        int c4 = (tid & 15) * 4;
        u16x4 o;
        o.x = f2bf(t[c4 + 0][l]); o.y = f2bf(t[c4 + 1][l]);
        o.z = f2bf(t[c4 + 2][l]); o.w = f2bf(t[c4 + 3][l]);
        *(u16x4*)&ob[(size_t)l * kC + c4] = o;
    }
}

// ---------------------------------------------------------------------------
// bf16 MFMA GEMM: D[m][n] = sum_k W[m][k]*X[b][n][k]
// BK=32, SINGLE barrier per K-step: {vmcnt(0); barrier; stage(t+1); compute}.
// Hoisted addressing, flat XCD-grouped grid for EPI 1/2.
// EPI: 1 = QKV route (q,k -> [L][C]; v -> [C][L]); bias0 = folded 1536-vec
//      2 = fp32 [C][L] + bias + residual (final)
//      3 = bf16 [m][n] row-major, no bias (weight-fold product, 3D grid)
// ---------------------------------------------------------------------------
template <int EPI>
__global__ __launch_bounds__(256, 4)
void gemm_mfma(const u16* __restrict__ W, const u16* __restrict__ X,
               const float* __restrict__ bias0,
               u16* __restrict__ o0, u16* __restrict__ o1, u16* __restrict__ o2,
               const float* __restrict__ resid, float* __restrict__ outf)
{
    __shared__ short lds[2][2][128 * 32];   // 32 KB total
    const int tid = threadIdx.x, lane = tid & 63, w = tid >> 6;
    const int l15 = lane & 15, l4 = lane >> 4;

    int bxi, byi, bb;
    if constexpr (EPI == 3) {
        bxi = blockIdx.x; byi = blockIdx.y; bb = blockIdx.z;
    } else {
        // flat grid: f%8 = XCD residue -> batches {2r, 2r+1}
        int f = blockIdx.x;
        int xcd = f & 7, i = f >> 3;
        bb = 2 * xcd + (i & 1);
        int j = i >> 1;
        byi = j >> 3; bxi = j & 7;
    }
    const int bm = byi * 128, bn = bxi * 128;
    const u16* Ag = W + (size_t)bm * kC;
    const u16* Bg = X + ((size_t)bb * kL + bn) * kC;
    const int wm = (w >> 1) * 64, wn = (w & 1) * 64;

    f4 acc[4][4] = {};

    // --- hoisted staging constants: 512 16B-units per matrix, 2/thread ---
    size_t ago[2];
    int ldd[2];
    #pragma unroll
    for (int i = 0; i < 2; ++i) {
        int unit = i * 256 + tid;
        int row = unit >> 2, pos = unit & 3;
        ago[i] = (size_t)row * kC + ((pos ^ (row & 3)) << 3);
        ldd[i] = unit * 8;
    }
    auto stage = [&](int kt, int bi) {
        #pragma unroll
        for (int i = 0; i < 2; ++i) {
            gload_lds16(Ag + ago[i] + kt, &lds[bi][0][ldd[i]]);
            gload_lds16(Bg + ago[i] + kt, &lds[bi][1][ldd[i]]);
        }
    };

    // --- hoisted fragment LDS offsets (rows of 32 shorts, 4 slots, XOR row&3)
    int aoff[4], boff[4];
    #pragma unroll
    for (int f = 0; f < 4; ++f) {
        int ra = wm + f * 16 + l15;
        aoff[f] = ra * 32 + ((l4 ^ (ra & 3)) << 3);
        int rb = wn + f * 16 + l15;
        boff[f] = rb * 32 + ((l4 ^ (rb & 3)) << 3);
    }

    stage(0, 0);

    for (int t = 0; t < 16; ++t) {
        const int cur = t & 1;
        // own loads (tile t) done; barrier => everyone's done => buf[cur]
        // fully populated AND all reads of buf[cur^1] (iter t-1) retired.
        asm volatile("s_waitcnt vmcnt(0)" ::: "memory");
        __builtin_amdgcn_s_barrier();
        if (t < 15) stage((t + 1) * 32, cur ^ 1);

        const short* La = &lds[cur][0][0];
        const short* Lb = &lds[cur][1][0];
        s8 af[4], bfr[4];
        #pragma unroll
        for (int f = 0; f < 4; ++f) {
            af[f]  = *(const s8*)(La + aoff[f]);
            bfr[f] = *(const s8*)(Lb + boff[f]);
        }
        __builtin_amdgcn_s_setprio(1);
        #pragma unroll
        for (int fi = 0; fi < 4; ++fi)
            #pragma unroll
            for (int fj = 0; fj < 4; ++fj)
                acc[fi][fj] = __builtin_amdgcn_mfma_f32_16x16x32_bf16(
                    af[fi], bfr[fj], acc[fi][fj], 0, 0, 0);
        __builtin_amdgcn_s_setprio(0);
    }

    #pragma unroll
    for (int fi = 0; fi < 4; ++fi) {
        const int mb = bm + wm + fi * 16 + 4 * l4;
        if constexpr (EPI == 2) {
            #pragma unroll
            for (int fj = 0; fj < 4; ++fj) {
                const int n = bn + wn + fj * 16 + l15;
                #pragma unroll
                for (int r = 0; r < 4; ++r) {
                    size_t idx = ((size_t)(bb * kC + mb + r)) * kL + n;
                    outf[idx] = acc[fi][fj][r] + bias0[mb + r] + resid[idx];
                }
            }
        } else if constexpr (EPI == 3) {
            #pragma unroll
            for (int fj = 0; fj < 4; ++fj) {
                const int n = bn + wn + fj * 16 + l15;
                #pragma unroll
                for (int r = 0; r < 4; ++r)
                    o0[(size_t)(mb + r) * kC + n] = f2bf(acc[fi][fj][r]);
            }
        } else {  // EPI == 1: QKV routing, bias0 = folded 1536-vector
            if (mb < 1024) {
                u16* dst = (mb < 512) ? o0 : o1;
                const int m2 = mb & 511;
                float bs[4] = {bias0[mb], bias0[mb + 1], bias0[mb + 2], bias0[mb + 3]};
                #pragma unroll
                for (int fj = 0; fj < 4; ++fj) {
                    const int n = bn + wn + fj * 16 + l15;
                    u16x4 pk;
                    #pragma unroll
                    for (int r = 0; r < 4; ++r) pk[r] = f2bf(acc[fi][fj][r] + bs[r]);
                    *(u16x4*)&dst[((size_t)(bb * kL + n)) * kC + m2] = pk;
                }
            } else {
                const int m2 = mb - 1024;   // V -> transposed [C][L]
                #pragma unroll
                for (int fj = 0; fj < 4; ++fj) {
                    const int n = bn + wn + fj * 16 + l15;
                    #pragma unroll
                    for (int r = 0; r < 4; ++r)
                        o2[((size_t)(bb * kC + m2 + r)) * kL + n] =
                            f2bf(acc[fi][fj][r] + bias0[mb + r]);
                }
            }
        }
    }
}

// ---------------------------------------------------------------------------
// Flash attention v12: r11's KVBLK=64 structure (measured 44 µs, no spill)
// with ONE register-reducing change kept from r13: lsum on the VALU pipe
// (f16v lsum -> scalar ls; frees ~15 VGPR and 4 of 20 MFMA/tile). KVBLK=128
// (r13) spilled to scratch: 231 MB writes, 111 µs — reverted.
// Raw v_exp_f32; single-barrier pipeline; unnormalized softmax; zero-shuffle
// PV via K-row permutation (swap b2,b3). 512 thr, __launch_bounds__(512,4).
// ---------------------------------------------------------------------------
__global__ __launch_bounds__(512, 4)
void attn_mfma(const u16* __restrict__ q, const u16* __restrict__ k,
               const u16* __restrict__ vt, u16* __restrict__ o)
{
    __shared__ short ldsK[2][32 * 128];   // [buf][j-pair row][128] swizzled
    __shared__ short ldsV[2][32 * 128];   // [buf][d-pair row][128] swizzled

    const int tid = threadIdx.x, lane = tid & 63, w = tid >> 6;   // w 0..7
    const int l31 = lane & 31, h5 = lane >> 5;

    // XCD grouping: all 4 q2-tiles of one (b,h) -> same flat%8 residue
    const int flat = blockIdx.x;                  // 512 blocks
    const int bh = (flat & 7) * 16 + (flat >> 5); // 0..127
    const int qt2 = (flat >> 3) & 3;
    const int b = bh >> 3, h = bh & 7;

    const size_t qrow0 = (size_t)b * kL + qt2 * 256 + w * 32;
    const u16* Qh = q + qrow0 * kC + h * 64;
    const u16* Kb = k + ((size_t)b * kL) * kC + h * 64;
    const u16* Vb = vt + ((size_t)b * kC + h * 64) * kL;

    s8 qf[4];
    #pragma unroll
    for (int ks = 0; ks < 4; ++ks) {
        s8 raw = *(const s8*)(Qh + (size_t)l31 * kC + ks * 16 + h5 * 8);
        #pragma unroll
        for (int e = 0; e < 8; e += 2) {
            u32 pk = pkbf(bf2f((u16)raw[e]) * kQScale,
                          bf2f((u16)raw[e + 1]) * kQScale);
            qf[ks][e]     = (short)(pk & 0xffff);
            qf[ks][e + 1] = (short)(pk >> 16);
        }
    }

    f16v oacc0 = {}, oacc1 = {};   // O^T rows d, col q = l31
    float ls = 0.f;                // in-lane partial softmax denominator

    // --- staging: 512 16B-units per tile, 1 K-load + 1 V-load per thread ---
    size_t kgo, vgo;
    int ldd;
    {
        int u_ = tid;
        int row = u_ >> 4, pos = u_ & 15;         // row 0..31 (pair index)
        int s = pos ^ (row & 15);
        int jd = row * 2 + (s >> 3);              // 0..63 (j for K, d for V)
        int jda = (jd & 51) | ((jd & 4) << 1) | ((jd & 8) >> 1);  // swap b2,b3
        int sub8 = (s & 7) << 3;
        kgo = (size_t)jda * kC + sub8;
        vgo = (size_t)jd * kL + sub8;
        ldd = u_ * 8;
    }
    auto stage = [&](int jt, int bi) {
        gload_lds16(Kb + kgo + (size_t)jt * (64 * kC), &ldsK[bi][ldd]);
        gload_lds16(Vb + vgo + jt * 64,                &ldsV[bi][ldd]);
    };

    const int sbase = (l31 & 1) << 3;
    const int rlo = l31 >> 1;
    int loff[4];
    #pragma unroll
    for (int ks = 0; ks < 4; ++ks) {
        int s_ = sbase | (2 * ks + h5);
        loff[ks] = rlo * 128 + ((s_ ^ (rlo & 15)) << 3);
    }

    stage(0, 0);

    for (int t = 0; t < 16; ++t) {
        const int cur = t & 1;
        // own loads (tile t) done; barrier => tile ready AND buf[cur^1]
        // reads (iter t-1) retired => safe to overwrite with tile t+1.
        asm volatile("s_waitcnt vmcnt(0)" ::: "memory");
        __builtin_amdgcn_s_barrier();
        if (t < 15) stage(t + 1, cur ^ 1);

        const short* Kl = ldsK[cur];
        const short* Vl = ldsV[cur];

        // S = K Q  (score-row s holds key pi(s); key-order invariant)
        f16v sf0 = {}, sf1 = {};
        __builtin_amdgcn_s_setprio(1);
        #pragma unroll
        for (int ks = 0; ks < 4; ++ks) {
            s8 kf0 = *(const s8*)(Kl + loff[ks]);
            s8 kf1 = *(const s8*)(Kl + loff[ks] + 2048);
            sf0 = __builtin_amdgcn_mfma_f32_32x32x16_bf16(kf0, qf[ks], sf0, 0, 0, 0);
            sf1 = __builtin_amdgcn_mfma_f32_32x32x16_bf16(kf1, qf[ks], sf1, 0, 0, 0);
        }
        __builtin_amdgcn_s_setprio(0);

        // P = exp2(S) — raw v_exp_f32; no max subtraction (bounded inputs)
        #pragma unroll
        for (int r = 0; r < 16; ++r) {
            sf0[r] = exp2hw(sf0[r]);
            sf1[r] = exp2hw(sf1[r]);
        }

        // lsum on the VALU pipe: 4-way ILP tree over this lane's 32 p's
        {
            float t0 = 0.f, t1 = 0.f, t2 = 0.f, t3 = 0.f;
            #pragma unroll
            for (int r = 0; r < 16; r += 4) {
                t0 += sf0[r];     t1 += sf0[r + 1];
                t2 += sf0[r + 2]; t3 += sf0[r + 3];
            }
            #pragma unroll
            for (int r = 0; r < 16; r += 4) {
                t0 += sf1[r];     t1 += sf1[r + 1];
                t2 += sf1[r + 2]; t3 += sf1[r + 3];
            }
            ls += (t0 + t1) + (t2 + t3);
        }

        // PV B-fragments: window ks = lane's own regs r0..r0+7 packed in order
        s8 pf[4];
        #pragma unroll
        for (int ks = 0; ks < 4; ++ks) {
            const f16v& pv = (ks < 2) ? sf0 : sf1;
            const int r0 = 8 * (ks & 1);
            union { u32 wd[4]; s8 v; } u;
            u.wd[0] = pkbf(pv[r0 + 0], pv[r0 + 1]);
            u.wd[1] = pkbf(pv[r0 + 2], pv[r0 + 3]);
            u.wd[2] = pkbf(pv[r0 + 4], pv[r0 + 5]);
            u.wd[3] = pkbf(pv[r0 + 6], pv[r0 + 7]);
            pf[ks] = u.v;
        }

        // O^T += V^T P
        __builtin_amdgcn_s_setprio(1);
        #pragma unroll
        for (int ks = 0; ks < 4; ++ks) {
            s8 vf0 = *(const s8*)(Vl + loff[ks]);
            s8 vf1 = *(const s8*)(Vl + loff[ks] + 2048);
            oacc0 = __builtin_amdgcn_mfma_f32_32x32x16_bf16(vf0, pf[ks], oacc0, 0, 0, 0);
            oacc1 = __builtin_amdgcn_mfma_f32_32x32x16_bf16(vf1, pf[ks], oacc1, 0, 0, 0);
        }
        __builtin_amdgcn_s_setprio(0);
    }

    // denominator: own 32-sum + partner half-lane's 32-sum
    const float inv = 1.0f / (ls + __shfl_xor(ls, 32));
    u16* orow = o + (qrow0 + l31) * kC + h * 64;
    #pragma unroll
    for (int db = 0; db < 2; ++db) {
        const f16v& oa = db ? oacc1 : oacc0;
        #pragma unroll
        for (int g = 0; g < 4; ++g) {
            int d0 = db * 32 + g * 8 + 4 * h5;
            u32 w0 = pkbf(oa[g * 4 + 0] * inv, oa[g * 4 + 1] * inv);
            u32 w1 = pkbf(oa[g * 4 + 2] * inv, oa[g * 4 + 3] * inv);
            u16x4 pk;
            pk[0] = (u16)(w0 & 0xffff); pk[1] = (u16)(w0 >> 16);
            pk[2] = (u16)(w1 & 0xffff); pk[3] = (u16)(w1 >> 16);
            *(u16x4*)&orow[d0] = pk;
        }
    }
}

// ---------------------------------------------------------------------------
extern "C" void kernel_launch(void* const* d_in, const int* in_sizes, int n_in,
                              void* d_out, int out_size, void* d_ws, size_t ws_size,
                              hipStream_t stream)
{
    const float* x      = (const float*)d_in[0];
    const float* gn_w   = (const float*)d_in[1];
    const float* gn_b   = (const float*)d_in[2];
    const float* conv_w = (const float*)d_in[3];
    const float* conv_b = (const float*)d_in[4];
    const float* wq     = (const float*)d_in[5];
    const float* bq     = (const float*)d_in[6];
    const float* wk     = (const float*)d_in[7];
    const float* bk     = (const float*)d_in[8];
    const float* wv     = (const float*)d_in[9];
    const float* bv     = (const float*)d_in[10];
    const float* wo     = (const float*)d_in[11];
    const float* bo     = (const float*)d_in[12];
    float* out = (float*)d_out;

    char* ws = (char*)d_ws;
    float2* stats = (float2*)ws;                       // 4 KB (8 KB reserved)
    u16* wqkvB  = (u16*)(ws + 8192);                   // 1.5 MB (q|k|v stacked)
    u16* woB    = wqkvB + 786432;                      // 0.5 MB (contiguous after wqkvB)
    u16* convwT = woB + 262144;                        // 0.5 MB
    u16* wqkvF  = convwT + 262144;                     // 1.5 MB (folded weights)
    float* bqkvF = (float*)(wqkvF + 786432);           // 6 KB
    const size_t ACT = (size_t)kB * kL * kC;
    u16* xt  = (u16*)(ws + (6 << 20));
    u16* qb  = xt + ACT;
    u16* kb  = qb + ACT;
    u16* vtb = kb + ACT;
    u16* res = xt;   // xt dead after QKV GEMM; reuse for attention output

    // --- fused prep: weight cvt + conv_w transpose + bias fold + GN stats ---
    prep1_kernel<<<1984, 256, 0, stream>>>(wq, wk, wv, wo, conv_w,
                                           bq, bk, bv, conv_b, x,
                                           wqkvB, convwT, bqkvF, stats);
    // W' = Wqkv @ conv_w   (fold 1x1 conv into QKV projections)
    gemm_mfma<3><<<dim3(4, 12, 1), 256, 0, stream>>>(
        wqkvB, convwT, nullptr, wqkvF, nullptr, nullptr, nullptr, nullptr);
    // GN-normalize + transpose input
    gn_t_kernel<<<dim3(16, 8, kB), 256, 0, stream>>>(x, stats, gn_w, gn_b, xt);

    // q,k,v (v transposed) from normalized input via folded weights (flat grid)
    gemm_mfma<1><<<1536, 256, 0, stream>>>(
        wqkvF, xt, bqkvF, qb, kb, vtb, nullptr, nullptr);
    attn_mfma<<<dim3(512), 512, 0, stream>>>(qb, kb, vtb, res);
    // out = wo @ res + bo + x  (flat grid)
    gemm_mfma<2><<<512, 256, 0, stream>>>(
        woB, res, bo, nullptr, nullptr, nullptr, x, out);
}

// Round 15
// 124.806 us; speedup vs baseline: 1.4913x; 1.0311x over previous
//
#include <hip/hip_runtime.h>
#include <math.h>

typedef __attribute__((ext_vector_type(4))) float f4;
typedef __attribute__((ext_vector_type(16))) float f16v;
typedef __attribute__((ext_vector_type(8))) short s8;      // 8 x bf16 fragment
typedef __attribute__((ext_vector_type(4))) unsigned short u16x4;
typedef unsigned short u16;
typedef unsigned int u32;

constexpr int kB = 16, kC = 512, kL = 1024, kNH = 8, kG = 32;
constexpr float kEps = 1e-5f;
constexpr float kQScale = 0.18033688011112042f;  // 0.125 * log2(e)

// fp32 -> bf16 RNE (scalar)
__device__ __forceinline__ u16 f2bf(float f) {
    union { float f; unsigned u; } c; c.f = f;
    unsigned u = c.u;
    return (u16)((u + 0x7fffu + ((u >> 16) & 1u)) >> 16);
}
__device__ __forceinline__ float bf2f(u16 v) {
    union { u32 u; float f; } c; c.u = (u32)v << 16; return c.f;
}
// packed 2x f32 -> 2x bf16 in one instr (lo in [15:0], hi in [31:16])
__device__ __forceinline__ u32 pkbf(float lo, float hi) {
    u32 r;
    asm("v_cvt_pk_bf16_f32 %0, %1, %2" : "=v"(r) : "v"(lo), "v"(hi));
    return r;
}
// raw hardware 2^x — single v_exp_f32, no OCML guard sequence
__device__ __forceinline__ float exp2hw(float x) {
    float r;
    asm("v_exp_f32 %0, %1" : "=v"(r) : "v"(x));
    return r;
}

// async global->LDS, 16B per lane. LDS dest = wave-uniform base + lane*16.
__device__ __forceinline__ void gload_lds16(const void* g, void* l) {
    __builtin_amdgcn_global_load_lds(
        (const __attribute__((address_space(1))) void*)g,
        (__attribute__((address_space(3))) void*)l, 16, 0, 0);
}

// ---------------------------------------------------------------------------
// Fused prep kernel (independent jobs, one launch):
//   blocks    0..1023 : wq|wk|wv|wo fp32 -> bf16 contiguous (wqkvB | woB)
//   blocks 1024..1087 : conv_w [c][e] -> transposed bf16 [e][c]
//   blocks 1088..1471 : folded bias b' = Wqkv@conv_b + b_qkv (fp32)
//   blocks 1472..1983 : GroupNorm stats per (b,g)
// ---------------------------------------------------------------------------
__global__ __launch_bounds__(256)
void prep1_kernel(const float* __restrict__ wq, const float* __restrict__ wk,
                  const float* __restrict__ wv, const float* __restrict__ wo,
                  const float* __restrict__ cw, const float* __restrict__ bq,
                  const float* __restrict__ bk, const float* __restrict__ bv,
                  const float* __restrict__ convb, const float* __restrict__ x,
                  u16* __restrict__ dst, u16* __restrict__ dstT,
                  float* __restrict__ outb, float2* __restrict__ stats)
{
    __shared__ float t[64][65];
    const int tid = threadIdx.x;
    const int bid = blockIdx.x;
    if (bid < 1024) {
        int idx = bid * 256 + tid;                    // float4 index
        int m = idx >> 16;
        int r = idx & 65535;
        const float* srcs[4] = {wq, wk, wv, wo};
        float4 v = ((const float4*)srcs[m])[r];
        u16x4 o; o.x = f2bf(v.x); o.y = f2bf(v.y); o.z = f2bf(v.z); o.w = f2bf(v.w);
        ((u16x4*)dst)[idx] = o;
    } else if (bid < 1088) {
        int b2 = bid - 1024;                          // 0..63
        const int c0 = (b2 >> 3) * 64, e0 = (b2 & 7) * 64;
        #pragma unroll
        for (int it = 0; it < 4; ++it) {
            int c = it * 16 + (tid >> 4);
            int e4 = (tid & 15) * 4;
            float4 v = *(const float4*)&cw[(size_t)(c0 + c) * kC + e0 + e4];
            t[c][e4 + 0] = v.x; t[c][e4 + 1] = v.y;
            t[c][e4 + 2] = v.z; t[c][e4 + 3] = v.w;
        }
        __syncthreads();
        #pragma unroll
        for (int it = 0; it < 4; ++it) {
            int e = it * 16 + (tid >> 4);
            int c4 = (tid & 15) * 4;
            u16x4 o;
            o.x = f2bf(t[c4 + 0][e]); o.y = f2bf(t[c4 + 1][e]);
            o.z = f2bf(t[c4 + 2][e]); o.w = f2bf(t[c4 + 3][e]);
            *(u16x4*)&dstT[(size_t)(e0 + e) * kC + c0 + c4] = o;
        }
    } else if (bid < 1472) {
        const int o = (bid - 1088) * 4 + (tid >> 6);  // 0..1535
        const int lane = tid & 63;
        const float* w; const float* borig; int m2;
        if (o < 512)       { w = wq; borig = bq; m2 = o; }
        else if (o < 1024) { w = wk; borig = bk; m2 = o - 512; }
        else               { w = wv; borig = bv; m2 = o - 1024; }
        const float* wr = w + (size_t)m2 * kC + lane * 8;
        const float* cb = convb + lane * 8;
        float4 a0 = *(const float4*)wr,  a1 = *(const float4*)(wr + 4);
        float4 b0 = *(const float4*)cb,  b1 = *(const float4*)(cb + 4);
        float s = a0.x * b0.x + a0.y * b0.y + a0.z * b0.z + a0.w * b0.w
                + a1.x * b1.x + a1.y * b1.y + a1.z * b1.z + a1.w * b1.w;
        #pragma unroll
        for (int off = 32; off > 0; off >>= 1) s += __shfl_down(s, off);
        if (lane == 0) outb[o] = s + borig[m2];
    } else {
        const int bg = bid - 1472;                    // 0..511
        const float4* p = (const float4*)(x + (size_t)bg * (16 * kL));
        float s = 0.f, ss = 0.f;
        for (int i = tid; i < (16 * kL) / 4; i += 256) {
            float4 v = p[i];
            s  += v.x + v.y + v.z + v.w;
            ss += v.x * v.x + v.y * v.y + v.z * v.z + v.w * v.w;
        }
        #pragma unroll
        for (int off = 32; off > 0; off >>= 1) {
            s  += __shfl_down(s, off);
            ss += __shfl_down(ss, off);
        }
        __shared__ float rs[4], rss[4];
        if ((tid & 63) == 0) { rs[tid >> 6] = s; rss[tid >> 6] = ss; }
        __syncthreads();
        if (tid == 0) {
            float S = rs[0] + rs[1] + rs[2] + rs[3];
            float SS = rss[0] + rss[1] + rss[2] + rss[3];
            const float inv_n = 1.f / (float)(16 * kL);
            float mean = S * inv_n;
            float var  = SS * inv_n - mean * mean;
            stats[bg] = make_float2(mean, rsqrtf(var + kEps));
        }
    }
}

// ---------------------------------------------------------------------------
// GN apply + transpose + bf16 cast:  x [B][C][L] fp32 -> xt [B][L][C] bf16
// ---------------------------------------------------------------------------
__global__ __launch_bounds__(256)
void gn_t_kernel(const float* __restrict__ x, const float2* __restrict__ stats,
                 const float* __restrict__ gnw, const float* __restrict__ gnb,
                 u16* __restrict__ xt)
{
    __shared__ float t[64][65];
    const int tid = threadIdx.x;
    const int b = blockIdx.z, c0 = blockIdx.y * 64, l0 = blockIdx.x * 64;
    const float* xb = x + ((size_t)(b * kC + c0)) * kL + l0;
    #pragma unroll
    for (int it = 0; it < 4; ++it) {
        int c = it * 16 + (tid >> 4);
        int l4i = (tid & 15) * 4;
        float4 v = *(const float4*)&xb[(size_t)c * kL + l4i];
        float2 st = stats[b * kG + ((c0 + c) >> 4)];
        float a  = st.y * gnw[c0 + c];
        float bb = gnb[c0 + c] - st.x * a;
        t[c][l4i + 0] = v.x * a + bb;
        t[c][l4i + 1] = v.y * a + bb;
        t[c][l4i + 2] = v.z * a + bb;
        t[c][l4i + 3] = v.w * a + bb;
    }
    __syncthreads();
    u16* ob = xt + ((size_t)(b * kL + l0)) * kC + c0;
    #pragma unroll
    for (int it = 0; it < 4; ++it) {
        int l = it * 16 + (tid >> 4);
        int c4 = (tid & 15) * 4;
        u16x4 o;
        o.x = f2bf(t[c4 + 0][l]); o.y = f2bf(t[c4 + 1][l]);
        o.z = f2bf(t[c4 + 2][l]); o.w = f2bf(t[c4 + 3][l]);
        *(u16x4*)&ob[(size_t)l * kC + c4] = o;
    }
}

// ---------------------------------------------------------------------------
// bf16 MFMA GEMM v2: D[m][n] = sum_k W[m][k]*X[b][n][k].  BK=32.
// LDS: PAIRED-ROW layout [64 pair-rows][64 shorts] per tile — two BK=32 rows
// share one 128B LDS row; 16B slot s0=(row&1)*4+k4 stored at s0^(pr&7).
// Any 8-consecutive-lane read group covers 8 distinct slots = 32 banks
// (attn-proven pattern; fixes r14's 3.1M bank conflicts from 64B rows).
// 3-deep pipeline (48KB LDS): {vmcnt(4); barrier; stage(t+2); compute(t)} —
// each stage gets ~2 compute phases of latency cover, never drains mid-loop.
// EPI: 1 = QKV route (q,k -> [L][C]; v -> [C][L]); bias0 = folded 1536-vec
//      2 = fp32 [C][L] + bias + residual (final)
//      3 = bf16 [m][n] row-major, no bias (weight-fold product, 3D grid)
// ---------------------------------------------------------------------------
template <int EPI>
__global__ __launch_bounds__(256, 4)
void gemm_mfma(const u16* __restrict__ W, const u16* __restrict__ X,
               const float* __restrict__ bias0,
               u16* __restrict__ o0, u16* __restrict__ o1, u16* __restrict__ o2,
               const float* __restrict__ resid, float* __restrict__ outf)
{
    __shared__ short lds[3][2][64 * 64];   // 48 KB total (3 bufs x A,B x 8KB)
    const int tid = threadIdx.x, lane = tid & 63, w = tid >> 6;
    const int l15 = lane & 15, l4 = lane >> 4;

    int bxi, byi, bb;
    if constexpr (EPI == 3) {
        bxi = blockIdx.x; byi = blockIdx.y; bb = blockIdx.z;
    } else {
        // flat grid: f%8 = XCD residue -> batches {2r, 2r+1}
        int f = blockIdx.x;
        int xcd = f & 7, i = f >> 3;
        bb = 2 * xcd + (i & 1);
        int j = i >> 1;
        byi = j >> 3; bxi = j & 7;
    }
    const int bm = byi * 128, bn = bxi * 128;
    const u16* Ag = W + (size_t)bm * kC;
    const u16* Bg = X + ((size_t)bb * kL + bn) * kC;
    const int wm = (w >> 1) * 64, wn = (w & 1) * 64;

    f4 acc[4][4] = {};

    // --- staging constants: 512 16B-units per tile, 2/thread; paired-row ---
    size_t ago[2];
    int ldd[2];
    #pragma unroll
    for (int i = 0; i < 2; ++i) {
        int u_ = i * 256 + tid;
        int pr = u_ >> 3, st = u_ & 7;
        int s0 = st ^ (pr & 7);                 // logical slot
        int row = 2 * pr + (s0 >> 2);           // logical tile row 0..127
        int koff = (s0 & 3) * 8;                // shorts within the 32-short row
        ago[i] = (size_t)row * kC + koff;
        ldd[i] = u_ * 8;                        // linear LDS dest
    }
    auto stage = [&](int kt, int bi) {
        #pragma unroll
        for (int i = 0; i < 2; ++i) {
            gload_lds16(Ag + ago[i] + kt, &lds[bi][0][ldd[i]]);
            gload_lds16(Bg + ago[i] + kt, &lds[bi][1][ldd[i]]);
        }
    };

    // --- fragment LDS offsets: ra -> pr=ra>>1, s0=(ra&1)*4+l4, ^ (pr&7) ---
    int aoff[4], boff[4];
    #pragma unroll
    for (int f = 0; f < 4; ++f) {
        int ra = wm + f * 16 + l15;
        int pa = ra >> 1;
        aoff[f] = pa * 64 + ((((ra & 1) * 4 + l4) ^ (pa & 7)) << 3);
        int rb = wn + f * 16 + l15;
        int pb = rb >> 1;
        boff[f] = pb * 64 + ((((rb & 1) * 4 + l4) ^ (pb & 7)) << 3);
    }

    stage(0, 0);
    stage(32, 1);

    int cur = 0;
    for (int t = 0; t < 16; ++t) {
        if (t < 15) {
            asm volatile("s_waitcnt vmcnt(4)" ::: "memory");  // tile t landed; t+1 in flight
        } else {
            asm volatile("s_waitcnt vmcnt(0)" ::: "memory");
        }
        __builtin_amdgcn_s_barrier();
        // barrier => all waves finished compute(t-1) => buf[(t+2)%3] free.
        int tgt = (cur >= 1) ? cur - 1 : 2;     // (cur+2)%3
        if (t < 14) stage((t + 2) * 32, tgt);

        const short* La = &lds[cur][0][0];
        const short* Lb = &lds[cur][1][0];
        s8 af[4], bfr[4];
        #pragma unroll
        for (int f = 0; f < 4; ++f) {
            af[f]  = *(const s8*)(La + aoff[f]);
            bfr[f] = *(const s8*)(Lb + boff[f]);
        }
        __builtin_amdgcn_s_setprio(1);
        #pragma unroll
        for (int fi = 0; fi < 4; ++fi)
            #pragma unroll
            for (int fj = 0; fj < 4; ++fj)
                acc[fi][fj] = __builtin_amdgcn_mfma_f32_16x16x32_bf16(
                    af[fi], bfr[fj], acc[fi][fj], 0, 0, 0);
        __builtin_amdgcn_s_setprio(0);

        cur = (cur == 2) ? 0 : cur + 1;
    }

    #pragma unroll
    for (int fi = 0; fi < 4; ++fi) {
        const int mb = bm + wm + fi * 16 + 4 * l4;
        if constexpr (EPI == 2) {
            #pragma unroll
            for (int fj = 0; fj < 4; ++fj) {
                const int n = bn + wn + fj * 16 + l15;
                #pragma unroll
                for (int r = 0; r < 4; ++r) {
                    size_t idx = ((size_t)(bb * kC + mb + r)) * kL + n;
                    outf[idx] = acc[fi][fj][r] + bias0[mb + r] + resid[idx];
                }
            }
        } else if constexpr (EPI == 3) {
            #pragma unroll
            for (int fj = 0; fj < 4; ++fj) {
                const int n = bn + wn + fj * 16 + l15;
                #pragma unroll
                for (int r = 0; r < 4; ++r)
                    o0[(size_t)(mb + r) * kC + n] = f2bf(acc[fi][fj][r]);
            }
        } else {  // EPI == 1: QKV routing, bias0 = folded 1536-vector
            if (mb < 1024) {
                u16* dst = (mb < 512) ? o0 : o1;
                const int m2 = mb & 511;
                float bs[4] = {bias0[mb], bias0[mb + 1], bias0[mb + 2], bias0[mb + 3]};
                #pragma unroll
                for (int fj = 0; fj < 4; ++fj) {
                    const int n = bn + wn + fj * 16 + l15;
                    u16x4 pk;
                    #pragma unroll
                    for (int r = 0; r < 4; ++r) pk[r] = f2bf(acc[fi][fj][r] + bs[r]);
                    *(u16x4*)&dst[((size_t)(bb * kL + n)) * kC + m2] = pk;
                }
            } else {
                const int m2 = mb - 1024;   // V -> transposed [C][L]
                #pragma unroll
                for (int fj = 0; fj < 4; ++fj) {
                    const int n = bn + wn + fj * 16 + l15;
                    #pragma unroll
                    for (int r = 0; r < 4; ++r)
                        o2[((size_t)(bb * kC + m2 + r)) * kL + n] =
                            f2bf(acc[fi][fj][r] + bias0[mb + r]);
                }
            }
        }
    }
}

// ---------------------------------------------------------------------------
// Flash attention v12 (unchanged from round 14; measured 45.2 us, 56 VGPR):
// KVBLK=64, lsum on VALU, raw v_exp_f32, single-barrier pipeline,
// unnormalized softmax, zero-shuffle PV via K-row permutation (swap b2,b3).
// ---------------------------------------------------------------------------
__global__ __launch_bounds__(512, 4)
void attn_mfma(const u16* __restrict__ q, const u16* __restrict__ k,
               const u16* __restrict__ vt, u16* __restrict__ o)
{
    __shared__ short ldsK[2][32 * 128];   // [buf][j-pair row][128] swizzled
    __shared__ short ldsV[2][32 * 128];   // [buf][d-pair row][128] swizzled

    const int tid = threadIdx.x, lane = tid & 63, w = tid >> 6;   // w 0..7
    const int l31 = lane & 31, h5 = lane >> 5;

    // XCD grouping: all 4 q2-tiles of one (b,h) -> same flat%8 residue
    const int flat = blockIdx.x;                  // 512 blocks
    const int bh = (flat & 7) * 16 + (flat >> 5); // 0..127
    const int qt2 = (flat >> 3) & 3;
    const int b = bh >> 3, h = bh & 7;

    const size_t qrow0 = (size_t)b * kL + qt2 * 256 + w * 32;
    const u16* Qh = q + qrow0 * kC + h * 64;
    const u16* Kb = k + ((size_t)b * kL) * kC + h * 64;
    const u16* Vb = vt + ((size_t)b * kC + h * 64) * kL;

    s8 qf[4];
    #pragma unroll
    for (int ks = 0; ks < 4; ++ks) {
        s8 raw = *(const s8*)(Qh + (size_t)l31 * kC + ks * 16 + h5 * 8);
        #pragma unroll
        for (int e = 0; e < 8; e += 2) {
            u32 pk = pkbf(bf2f((u16)raw[e]) * kQScale,
                          bf2f((u16)raw[e + 1]) * kQScale);
            qf[ks][e]     = (short)(pk & 0xffff);
            qf[ks][e + 1] = (short)(pk >> 16);
        }
    }

    f16v oacc0 = {}, oacc1 = {};   // O^T rows d, col q = l31
    float ls = 0.f;                // in-lane partial softmax denominator

    // --- staging: 512 16B-units per tile, 1 K-load + 1 V-load per thread ---
    size_t kgo, vgo;
    int ldd;
    {
        int u_ = tid;
        int row = u_ >> 4, pos = u_ & 15;         // row 0..31 (pair index)
        int s = pos ^ (row & 15);
        int jd = row * 2 + (s >> 3);              // 0..63 (j for K, d for V)
        int jda = (jd & 51) | ((jd & 4) << 1) | ((jd & 8) >> 1);  // swap b2,b3
        int sub8 = (s & 7) << 3;
        kgo = (size_t)jda * kC + sub8;
        vgo = (size_t)jd * kL + sub8;
        ldd = u_ * 8;
    }
    auto stage = [&](int jt, int bi) {
        gload_lds16(Kb + kgo + (size_t)jt * (64 * kC), &ldsK[bi][ldd]);
        gload_lds16(Vb + vgo + jt * 64,                &ldsV[bi][ldd]);
    };

    const int sbase = (l31 & 1) << 3;
    const int rlo = l31 >> 1;
    int loff[4];
    #pragma unroll
    for (int ks = 0; ks < 4; ++ks) {
        int s_ = sbase | (2 * ks + h5);
        loff[ks] = rlo * 128 + ((s_ ^ (rlo & 15)) << 3);
    }

    stage(0, 0);

    for (int t = 0; t < 16; ++t) {
        const int cur = t & 1;
        asm volatile("s_waitcnt vmcnt(0)" ::: "memory");
        __builtin_amdgcn_s_barrier();
        if (t < 15) stage(t + 1, cur ^ 1);

        const short* Kl = ldsK[cur];
        const short* Vl = ldsV[cur];

        // S = K Q  (score-row s holds key pi(s); key-order invariant)
        f16v sf0 = {}, sf1 = {};
        __builtin_amdgcn_s_setprio(1);
        #pragma unroll
        for (int ks = 0; ks < 4; ++ks) {
            s8 kf0 = *(const s8*)(Kl + loff[ks]);
            s8 kf1 = *(const s8*)(Kl + loff[ks] + 2048);
            sf0 = __builtin_amdgcn_mfma_f32_32x32x16_bf16(kf0, qf[ks], sf0, 0, 0, 0);
            sf1 = __builtin_amdgcn_mfma_f32_32x32x16_bf16(kf1, qf[ks], sf1, 0, 0, 0);
        }
        __builtin_amdgcn_s_setprio(0);

        // P = exp2(S) — raw v_exp_f32; no max subtraction (bounded inputs)
        #pragma unroll
        for (int r = 0; r < 16; ++r) {
            sf0[r] = exp2hw(sf0[r]);
            sf1[r] = exp2hw(sf1[r]);
        }

        // lsum on the VALU pipe: 4-way ILP tree over this lane's 32 p's
        {
            float t0 = 0.f, t1 = 0.f, t2 = 0.f, t3 = 0.f;
            #pragma unroll
            for (int r = 0; r < 16; r += 4) {
                t0 += sf0[r];     t1 += sf0[r + 1];
                t2 += sf0[r + 2]; t3 += sf0[r + 3];
            }
            #pragma unroll
            for (int r = 0; r < 16; r += 4) {
                t0 += sf1[r];     t1 += sf1[r + 1];
                t2 += sf1[r + 2]; t3 += sf1[r + 3];
            }
            ls += (t0 + t1) + (t2 + t3);
        }

        // PV B-fragments: window ks = lane's own regs r0..r0+7 packed in order
        s8 pf[4];
        #pragma unroll
        for (int ks = 0; ks < 4; ++ks) {
            const f16v& pv = (ks < 2) ? sf0 : sf1;
            const int r0 = 8 * (ks & 1);
            union { u32 wd[4]; s8 v; } u;
            u.wd[0] = pkbf(pv[r0 + 0], pv[r0 + 1]);
            u.wd[1] = pkbf(pv[r0 + 2], pv[r0 + 3]);
            u.wd[2] = pkbf(pv[r0 + 4], pv[r0 + 5]);
            u.wd[3] = pkbf(pv[r0 + 6], pv[r0 + 7]);
            pf[ks] = u.v;
        }

        // O^T += V^T P
        __builtin_amdgcn_s_setprio(1);
        #pragma unroll
        for (int ks = 0; ks < 4; ++ks) {
            s8 vf0 = *(const s8*)(Vl + loff[ks]);
            s8 vf1 = *(const s8*)(Vl + loff[ks] + 2048);
            oacc0 = __builtin_amdgcn_mfma_f32_32x32x16_bf16(vf0, pf[ks], oacc0, 0, 0, 0);
            oacc1 = __builtin_amdgcn_mfma_f32_32x32x16_bf16(vf1, pf[ks], oacc1, 0, 0, 0);
        }
        __builtin_amdgcn_s_setprio(0);
    }

    // denominator: own 32-sum + partner half-lane's 32-sum
    const float inv = 1.0f / (ls + __shfl_xor(ls, 32));
    u16* orow = o + (qrow0 + l31) * kC + h * 64;
    #pragma unroll
    for (int db = 0; db < 2; ++db) {
        const f16v& oa = db ? oacc1 : oacc0;
        #pragma unroll
        for (int g = 0; g < 4; ++g) {
            int d0 = db * 32 + g * 8 + 4 * h5;
            u32 w0 = pkbf(oa[g * 4 + 0] * inv, oa[g * 4 + 1] * inv);
            u32 w1 = pkbf(oa[g * 4 + 2] * inv, oa[g * 4 + 3] * inv);
            u16x4 pk;
            pk[0] = (u16)(w0 & 0xffff); pk[1] = (u16)(w0 >> 16);
            pk[2] = (u16)(w1 & 0xffff); pk[3] = (u16)(w1 >> 16);
            *(u16x4*)&orow[d0] = pk;
        }
    }
}

// ---------------------------------------------------------------------------
extern "C" void kernel_launch(void* const* d_in, const int* in_sizes, int n_in,
                              void* d_out, int out_size, void* d_ws, size_t ws_size,
                              hipStream_t stream)
{
    const float* x      = (const float*)d_in[0];
    const float* gn_w   = (const float*)d_in[1];
    const float* gn_b   = (const float*)d_in[2];
    const float* conv_w = (const float*)d_in[3];
    const float* conv_b = (const float*)d_in[4];
    const float* wq     = (const float*)d_in[5];
    const float* bq     = (const float*)d_in[6];
    const float* wk     = (const float*)d_in[7];
    const float* bk     = (const float*)d_in[8];
    const float* wv     = (const float*)d_in[9];
    const float* bv     = (const float*)d_in[10];
    const float* wo     = (const float*)d_in[11];
    const float* bo     = (const float*)d_in[12];
    float* out = (float*)d_out;

    char* ws = (char*)d_ws;
    float2* stats = (float2*)ws;                       // 4 KB (8 KB reserved)
    u16* wqkvB  = (u16*)(ws + 8192);                   // 1.5 MB (q|k|v stacked)
    u16* woB    = wqkvB + 786432;                      // 0.5 MB (contiguous after wqkvB)
    u16* convwT = woB + 262144;                        // 0.5 MB
    u16* wqkvF  = convwT + 262144;                     // 1.5 MB (folded weights)
    float* bqkvF = (float*)(wqkvF + 786432);           // 6 KB
    const size_t ACT = (size_t)kB * kL * kC;
    u16* xt  = (u16*)(ws + (6 << 20));
    u16* qb  = xt + ACT;
    u16* kb  = qb + ACT;
    u16* vtb = kb + ACT;
    u16* res = xt;   // xt dead after QKV GEMM; reuse for attention output

    // --- fused prep: weight cvt + conv_w transpose + bias fold + GN stats ---
    prep1_kernel<<<1984, 256, 0, stream>>>(wq, wk, wv, wo, conv_w,
                                           bq, bk, bv, conv_b, x,
                                           wqkvB, convwT, bqkvF, stats);
    // W' = Wqkv @ conv_w   (fold 1x1 conv into QKV projections)
    gemm_mfma<3><<<dim3(4, 12, 1), 256, 0, stream>>>(
        wqkvB, convwT, nullptr, wqkvF, nullptr, nullptr, nullptr, nullptr);
    // GN-normalize + transpose input
    gn_t_kernel<<<dim3(16, 8, kB), 256, 0, stream>>>(x, stats, gn_w, gn_b, xt);

    // q,k,v (v transposed) from normalized input via folded weights (flat grid)
    gemm_mfma<1><<<1536, 256, 0, stream>>>(
        wqkvF, xt, bqkvF, qb, kb, vtb, nullptr, nullptr);
    attn_mfma<<<dim3(512), 512, 0, stream>>>(qb, kb, vtb, res);
    // out = wo @ res + bo + x  (flat grid)
    gemm_mfma<2><<<512, 256, 0, stream>>>(
        woB, res, bo, nullptr, nullptr, nullptr, x, out);
}

// Round 16
// 124.481 us; speedup vs baseline: 1.4952x; 1.0026x over previous
//
#include <hip/hip_runtime.h>
#include <math.h>

typedef __attribute__((ext_vector_type(4))) float f4;
typedef __attribute__((ext_vector_type(16))) float f16v;
typedef __attribute__((ext_vector_type(8))) short s8;      // 8 x bf16 fragment
typedef __attribute__((ext_vector_type(4))) unsigned short u16x4;
typedef unsigned short u16;
typedef unsigned int u32;

constexpr int kB = 16, kC = 512, kL = 1024, kNH = 8, kG = 32;
constexpr float kEps = 1e-5f;
constexpr float kQScale = 0.18033688011112042f;  // 0.125 * log2(e)

// fp32 -> bf16 RNE (scalar)
__device__ __forceinline__ u16 f2bf(float f) {
    union { float f; unsigned u; } c; c.f = f;
    unsigned u = c.u;
    return (u16)((u + 0x7fffu + ((u >> 16) & 1u)) >> 16);
}
__device__ __forceinline__ float bf2f(u16 v) {
    union { u32 u; float f; } c; c.u = (u32)v << 16; return c.f;
}
// packed 2x f32 -> 2x bf16 in one instr (lo in [15:0], hi in [31:16])
__device__ __forceinline__ u32 pkbf(float lo, float hi) {
    u32 r;
    asm("v_cvt_pk_bf16_f32 %0, %1, %2" : "=v"(r) : "v"(lo), "v"(hi));
    return r;
}
// raw hardware 2^x — single v_exp_f32, no OCML guard sequence
__device__ __forceinline__ float exp2hw(float x) {
    float r;
    asm("v_exp_f32 %0, %1" : "=v"(r) : "v"(x));
    return r;
}

// async global->LDS, 16B per lane. LDS dest = wave-uniform base + lane*16.
__device__ __forceinline__ void gload_lds16(const void* g, void* l) {
    __builtin_amdgcn_global_load_lds(
        (const __attribute__((address_space(1))) void*)g,
        (__attribute__((address_space(3))) void*)l, 16, 0, 0);
}

// ---------------------------------------------------------------------------
// Fused prep kernel (independent jobs, one launch):
//   blocks    0..1023 : wq|wk|wv|wo fp32 -> bf16 contiguous (wqkvB | woB)
//   blocks 1024..1087 : conv_w [c][e] -> transposed bf16 [e][c]
//   blocks 1088..1471 : folded bias b' = Wqkv@conv_b + b_qkv (fp32)
//   blocks 1472..1983 : GroupNorm stats per (b,g)
// ---------------------------------------------------------------------------
__global__ __launch_bounds__(256)
void prep1_kernel(const float* __restrict__ wq, const float* __restrict__ wk,
                  const float* __restrict__ wv, const float* __restrict__ wo,
                  const float* __restrict__ cw, const float* __restrict__ bq,
                  const float* __restrict__ bk, const float* __restrict__ bv,
                  const float* __restrict__ convb, const float* __restrict__ x,
                  u16* __restrict__ dst, u16* __restrict__ dstT,
                  float* __restrict__ outb, float2* __restrict__ stats)
{
    __shared__ float t[64][65];
    const int tid = threadIdx.x;
    const int bid = blockIdx.x;
    if (bid < 1024) {
        int idx = bid * 256 + tid;                    // float4 index
        int m = idx >> 16;
        int r = idx & 65535;
        const float* srcs[4] = {wq, wk, wv, wo};
        float4 v = ((const float4*)srcs[m])[r];
        u16x4 o; o.x = f2bf(v.x); o.y = f2bf(v.y); o.z = f2bf(v.z); o.w = f2bf(v.w);
        ((u16x4*)dst)[idx] = o;
    } else if (bid < 1088) {
        int b2 = bid - 1024;                          // 0..63
        const int c0 = (b2 >> 3) * 64, e0 = (b2 & 7) * 64;
        #pragma unroll
        for (int it = 0; it < 4; ++it) {
            int c = it * 16 + (tid >> 4);
            int e4 = (tid & 15) * 4;
            float4 v = *(const float4*)&cw[(size_t)(c0 + c) * kC + e0 + e4];
            t[c][e4 + 0] = v.x; t[c][e4 + 1] = v.y;
            t[c][e4 + 2] = v.z; t[c][e4 + 3] = v.w;
        }
        __syncthreads();
        #pragma unroll
        for (int it = 0; it < 4; ++it) {
            int e = it * 16 + (tid >> 4);
            int c4 = (tid & 15) * 4;
            u16x4 o;
            o.x = f2bf(t[c4 + 0][e]); o.y = f2bf(t[c4 + 1][e]);
            o.z = f2bf(t[c4 + 2][e]); o.w = f2bf(t[c4 + 3][e]);
            *(u16x4*)&dstT[(size_t)(e0 + e) * kC + c0 + c4] = o;
        }
    } else if (bid < 1472) {
        const int o = (bid - 1088) * 4 + (tid >> 6);  // 0..1535
        const int lane = tid & 63;
        const float* w; const float* borig; int m2;
        if (o < 512)       { w = wq; borig = bq; m2 = o; }
        else if (o < 1024) { w = wk; borig = bk; m2 = o - 512; }
        else               { w = wv; borig = bv; m2 = o - 1024; }
        const float* wr = w + (size_t)m2 * kC + lane * 8;
        const float* cb = convb + lane * 8;
        float4 a0 = *(const float4*)wr,  a1 = *(const float4*)(wr + 4);
        float4 b0 = *(const float4*)cb,  b1 = *(const float4*)(cb + 4);
        float s = a0.x * b0.x + a0.y * b0.y + a0.z * b0.z + a0.w * b0.w
                + a1.x * b1.x + a1.y * b1.y + a1.z * b1.z + a1.w * b1.w;
        #pragma unroll
        for (int off = 32; off > 0; off >>= 1) s += __shfl_down(s, off);
        if (lane == 0) outb[o] = s + borig[m2];
    } else {
        const int bg = bid - 1472;                    // 0..511
        const float4* p = (const float4*)(x + (size_t)bg * (16 * kL));
        float s = 0.f, ss = 0.f;
        for (int i = tid; i < (16 * kL) / 4; i += 256) {
            float4 v = p[i];
            s  += v.x + v.y + v.z + v.w;
            ss += v.x * v.x + v.y * v.y + v.z * v.z + v.w * v.w;
        }
        #pragma unroll
        for (int off = 32; off > 0; off >>= 1) {
            s  += __shfl_down(s, off);
            ss += __shfl_down(ss, off);
        }
        __shared__ float rs[4], rss[4];
        if ((tid & 63) == 0) { rs[tid >> 6] = s; rss[tid >> 6] = ss; }
        __syncthreads();
        if (tid == 0) {
            float S = rs[0] + rs[1] + rs[2] + rs[3];
            float SS = rss[0] + rss[1] + rss[2] + rss[3];
            const float inv_n = 1.f / (float)(16 * kL);
            float mean = S * inv_n;
            float var  = SS * inv_n - mean * mean;
            stats[bg] = make_float2(mean, rsqrtf(var + kEps));
        }
    }
}

// ---------------------------------------------------------------------------
// GN apply + transpose + bf16 cast:  x [B][C][L] fp32 -> xt [B][L][C] bf16
// ---------------------------------------------------------------------------
__global__ __launch_bounds__(256)
void gn_t_kernel(const float* __restrict__ x, const float2* __restrict__ stats,
                 const float* __restrict__ gnw, const float* __restrict__ gnb,
                 u16* __restrict__ xt)
{
    __shared__ float t[64][65];
    const int tid = threadIdx.x;
    const int b = blockIdx.z, c0 = blockIdx.y * 64, l0 = blockIdx.x * 64;
    const float* xb = x + ((size_t)(b * kC + c0)) * kL + l0;
    #pragma unroll
    for (int it = 0; it < 4; ++it) {
        int c = it * 16 + (tid >> 4);
        int l4i = (tid & 15) * 4;
        float4 v = *(const float4*)&xb[(size_t)c * kL + l4i];
        float2 st = stats[b * kG + ((c0 + c) >> 4)];
        float a  = st.y * gnw[c0 + c];
        float bb = gnb[c0 + c] - st.x * a;
        t[c][l4i + 0] = v.x * a + bb;
        t[c][l4i + 1] = v.y * a + bb;
        t[c][l4i + 2] = v.z * a + bb;
        t[c][l4i + 3] = v.w * a + bb;
    }
    __syncthreads();
    u16* ob = xt + ((size_t)(b * kL + l0)) * kC + c0;
    #pragma unroll
    for (int it = 0; it < 4; ++it) {
        int l = it * 16 + (tid >> 4);
        int c4 = (tid & 15) * 4;
        u16x4 o;
        o.x = f2bf(t[c4 + 0][l]); o.y = f2bf(t[c4 + 1][l]);
        o.z = f2bf(t[c4 + 2][l]); o.w = f2bf(t[c4 + 3][l]);
        *(u16x4*)&ob[(size_t)l * kC + c4] = o;
    }
}

// ---------------------------------------------------------------------------
// bf16 MFMA GEMM v2 (unchanged from round 15): paired-row LDS (conflict-free),
// BK=32, 3-deep pipeline {vmcnt(4); barrier; stage(t+2); compute(t)}.
// EPI: 1 = QKV route (q,k -> [L][C]; v -> [C][L]); bias0 = folded 1536-vec
//      2 = fp32 [C][L] + bias + residual (final)
//      3 = bf16 [m][n] row-major, no bias (weight-fold product, 3D grid)
// ---------------------------------------------------------------------------
template <int EPI>
__global__ __launch_bounds__(256, 4)
void gemm_mfma(const u16* __restrict__ W, const u16* __restrict__ X,
               const float* __restrict__ bias0,
               u16* __restrict__ o0, u16* __restrict__ o1, u16* __restrict__ o2,
               const float* __restrict__ resid, float* __restrict__ outf)
{
    __shared__ short lds[3][2][64 * 64];   // 48 KB total (3 bufs x A,B x 8KB)
    const int tid = threadIdx.x, lane = tid & 63, w = tid >> 6;
    const int l15 = lane & 15, l4 = lane >> 4;

    int bxi, byi, bb;
    if constexpr (EPI == 3) {
        bxi = blockIdx.x; byi = blockIdx.y; bb = blockIdx.z;
    } else {
        // flat grid: f%8 = XCD residue -> batches {2r, 2r+1}
        int f = blockIdx.x;
        int xcd = f & 7, i = f >> 3;
        bb = 2 * xcd + (i & 1);
        int j = i >> 1;
        byi = j >> 3; bxi = j & 7;
    }
    const int bm = byi * 128, bn = bxi * 128;
    const u16* Ag = W + (size_t)bm * kC;
    const u16* Bg = X + ((size_t)bb * kL + bn) * kC;
    const int wm = (w >> 1) * 64, wn = (w & 1) * 64;

    f4 acc[4][4] = {};

    // --- staging constants: 512 16B-units per tile, 2/thread; paired-row ---
    size_t ago[2];
    int ldd[2];
    #pragma unroll
    for (int i = 0; i < 2; ++i) {
        int u_ = i * 256 + tid;
        int pr = u_ >> 3, st = u_ & 7;
        int s0 = st ^ (pr & 7);                 // logical slot
        int row = 2 * pr + (s0 >> 2);           // logical tile row 0..127
        int koff = (s0 & 3) * 8;                // shorts within the 32-short row
        ago[i] = (size_t)row * kC + koff;
        ldd[i] = u_ * 8;                        // linear LDS dest
    }
    auto stage = [&](int kt, int bi) {
        #pragma unroll
        for (int i = 0; i < 2; ++i) {
            gload_lds16(Ag + ago[i] + kt, &lds[bi][0][ldd[i]]);
            gload_lds16(Bg + ago[i] + kt, &lds[bi][1][ldd[i]]);
        }
    };

    // --- fragment LDS offsets: ra -> pr=ra>>1, s0=(ra&1)*4+l4, ^ (pr&7) ---
    int aoff[4], boff[4];
    #pragma unroll
    for (int f = 0; f < 4; ++f) {
        int ra = wm + f * 16 + l15;
        int pa = ra >> 1;
        aoff[f] = pa * 64 + ((((ra & 1) * 4 + l4) ^ (pa & 7)) << 3);
        int rb = wn + f * 16 + l15;
        int pb = rb >> 1;
        boff[f] = pb * 64 + ((((rb & 1) * 4 + l4) ^ (pb & 7)) << 3);
    }

    stage(0, 0);
    stage(32, 1);

    int cur = 0;
    for (int t = 0; t < 16; ++t) {
        if (t < 15) {
            asm volatile("s_waitcnt vmcnt(4)" ::: "memory");  // tile t landed; t+1 in flight
        } else {
            asm volatile("s_waitcnt vmcnt(0)" ::: "memory");
        }
        __builtin_amdgcn_s_barrier();
        // barrier => all waves finished compute(t-1) => buf[(t+2)%3] free.
        int tgt = (cur >= 1) ? cur - 1 : 2;     // (cur+2)%3
        if (t < 14) stage((t + 2) * 32, tgt);

        const short* La = &lds[cur][0][0];
        const short* Lb = &lds[cur][1][0];
        s8 af[4], bfr[4];
        #pragma unroll
        for (int f = 0; f < 4; ++f) {
            af[f]  = *(const s8*)(La + aoff[f]);
            bfr[f] = *(const s8*)(Lb + boff[f]);
        }
        __builtin_amdgcn_s_setprio(1);
        #pragma unroll
        for (int fi = 0; fi < 4; ++fi)
            #pragma unroll
            for (int fj = 0; fj < 4; ++fj)
                acc[fi][fj] = __builtin_amdgcn_mfma_f32_16x16x32_bf16(
                    af[fi], bfr[fj], acc[fi][fj], 0, 0, 0);
        __builtin_amdgcn_s_setprio(0);

        cur = (cur == 2) ? 0 : cur + 1;
    }

    #pragma unroll
    for (int fi = 0; fi < 4; ++fi) {
        const int mb = bm + wm + fi * 16 + 4 * l4;
        if constexpr (EPI == 2) {
            #pragma unroll
            for (int fj = 0; fj < 4; ++fj) {
                const int n = bn + wn + fj * 16 + l15;
                #pragma unroll
                for (int r = 0; r < 4; ++r) {
                    size_t idx = ((size_t)(bb * kC + mb + r)) * kL + n;
                    outf[idx] = acc[fi][fj][r] + bias0[mb + r] + resid[idx];
                }
            }
        } else if constexpr (EPI == 3) {
            #pragma unroll
            for (int fj = 0; fj < 4; ++fj) {
                const int n = bn + wn + fj * 16 + l15;
                #pragma unroll
                for (int r = 0; r < 4; ++r)
                    o0[(size_t)(mb + r) * kC + n] = f2bf(acc[fi][fj][r]);
            }
        } else {  // EPI == 1: QKV routing, bias0 = folded 1536-vector
            if (mb < 1024) {
                u16* dst = (mb < 512) ? o0 : o1;
                const int m2 = mb & 511;
                float bs[4] = {bias0[mb], bias0[mb + 1], bias0[mb + 2], bias0[mb + 3]};
                #pragma unroll
                for (int fj = 0; fj < 4; ++fj) {
                    const int n = bn + wn + fj * 16 + l15;
                    u16x4 pk;
                    #pragma unroll
                    for (int r = 0; r < 4; ++r) pk[r] = f2bf(acc[fi][fj][r] + bs[r]);
                    *(u16x4*)&dst[((size_t)(bb * kL + n)) * kC + m2] = pk;
                }
            } else {
                const int m2 = mb - 1024;   // V -> transposed [C][L]
                #pragma unroll
                for (int fj = 0; fj < 4; ++fj) {
                    const int n = bn + wn + fj * 16 + l15;
                    #pragma unroll
                    for (int r = 0; r < 4; ++r)
                        o2[((size_t)(bb * kC + m2 + r)) * kL + n] =
                            f2bf(acc[fi][fj][r] + bias0[mb + r]);
                }
            }
        }
    }
}

// ---------------------------------------------------------------------------
// Flash attention v13: 3-BUFFER pipeline, prefetch distance 2 (GEMM-proven
// this round): {vmcnt(2); barrier; stage(t+2); compute(t)}. Tile t's loads
// get ~2 compute phases + barrier of latency cover; the mid-loop wait keeps
// tile t+1's loads in flight (never drains). LDS 48KB (2 blocks/CU -> 96KB).
// Overwrite safety: barrier at iter t => compute(t-1) reads retired =>
// buf[(t+2)%3] = buf[(t-1)%3] is free.
// Rest unchanged: KVBLK=64, lsum on VALU, raw v_exp_f32, unnormalized
// softmax, zero-shuffle PV via K-row permutation (swap b2,b3).
// ---------------------------------------------------------------------------
__global__ __launch_bounds__(512, 4)
void attn_mfma(const u16* __restrict__ q, const u16* __restrict__ k,
               const u16* __restrict__ vt, u16* __restrict__ o)
{
    __shared__ short ldsK[3][32 * 128];   // [buf][j-pair row][128] swizzled
    __shared__ short ldsV[3][32 * 128];   // [buf][d-pair row][128] swizzled

    const int tid = threadIdx.x, lane = tid & 63, w = tid >> 6;   // w 0..7
    const int l31 = lane & 31, h5 = lane >> 5;

    // XCD grouping: all 4 q2-tiles of one (b,h) -> same flat%8 residue
    const int flat = blockIdx.x;                  // 512 blocks
    const int bh = (flat & 7) * 16 + (flat >> 5); // 0..127
    const int qt2 = (flat >> 3) & 3;
    const int b = bh >> 3, h = bh & 7;

    const size_t qrow0 = (size_t)b * kL + qt2 * 256 + w * 32;
    const u16* Qh = q + qrow0 * kC + h * 64;
    const u16* Kb = k + ((size_t)b * kL) * kC + h * 64;
    const u16* Vb = vt + ((size_t)b * kC + h * 64) * kL;

    s8 qf[4];
    #pragma unroll
    for (int ks = 0; ks < 4; ++ks) {
        s8 raw = *(const s8*)(Qh + (size_t)l31 * kC + ks * 16 + h5 * 8);
        #pragma unroll
        for (int e = 0; e < 8; e += 2) {
            u32 pk = pkbf(bf2f((u16)raw[e]) * kQScale,
                          bf2f((u16)raw[e + 1]) * kQScale);
            qf[ks][e]     = (short)(pk & 0xffff);
            qf[ks][e + 1] = (short)(pk >> 16);
        }
    }

    f16v oacc0 = {}, oacc1 = {};   // O^T rows d, col q = l31
    float ls = 0.f;                // in-lane partial softmax denominator

    // --- staging: 512 16B-units per tile, 1 K-load + 1 V-load per thread ---
    size_t kgo, vgo;
    int ldd;
    {
        int u_ = tid;
        int row = u_ >> 4, pos = u_ & 15;         // row 0..31 (pair index)
        int s = pos ^ (row & 15);
        int jd = row * 2 + (s >> 3);              // 0..63 (j for K, d for V)
        int jda = (jd & 51) | ((jd & 4) << 1) | ((jd & 8) >> 1);  // swap b2,b3
        int sub8 = (s & 7) << 3;
        kgo = (size_t)jda * kC + sub8;
        vgo = (size_t)jd * kL + sub8;
        ldd = u_ * 8;
    }
    auto stage = [&](int jt, int bi) {
        gload_lds16(Kb + kgo + (size_t)jt * (64 * kC), &ldsK[bi][ldd]);
        gload_lds16(Vb + vgo + jt * 64,                &ldsV[bi][ldd]);
    };

    const int sbase = (l31 & 1) << 3;
    const int rlo = l31 >> 1;
    int loff[4];
    #pragma unroll
    for (int ks = 0; ks < 4; ++ks) {
        int s_ = sbase | (2 * ks + h5);
        loff[ks] = rlo * 128 + ((s_ ^ (rlo & 15)) << 3);
    }

    stage(0, 0);
    stage(1, 1);

    int cur = 0;
    for (int t = 0; t < 16; ++t) {
        if (t < 15) {
            asm volatile("s_waitcnt vmcnt(2)" ::: "memory");  // tile t landed; t+1 in flight
        } else {
            asm volatile("s_waitcnt vmcnt(0)" ::: "memory");
        }
        __builtin_amdgcn_s_barrier();
        // barrier => compute(t-1) reads retired => buf[(t+2)%3] free.
        int tgt = (cur >= 1) ? cur - 1 : 2;     // (cur+2)%3
        if (t < 14) stage(t + 2, tgt);

        const short* Kl = ldsK[cur];
        const short* Vl = ldsV[cur];

        // S = K Q  (score-row s holds key pi(s); key-order invariant)
        f16v sf0 = {}, sf1 = {};
        __builtin_amdgcn_s_setprio(1);
        #pragma unroll
        for (int ks = 0; ks < 4; ++ks) {
            s8 kf0 = *(const s8*)(Kl + loff[ks]);
            s8 kf1 = *(const s8*)(Kl + loff[ks] + 2048);
            sf0 = __builtin_amdgcn_mfma_f32_32x32x16_bf16(kf0, qf[ks], sf0, 0, 0, 0);
            sf1 = __builtin_amdgcn_mfma_f32_32x32x16_bf16(kf1, qf[ks], sf1, 0, 0, 0);
        }
        __builtin_amdgcn_s_setprio(0);

        // P = exp2(S) — raw v_exp_f32; no max subtraction (bounded inputs)
        #pragma unroll
        for (int r = 0; r < 16; ++r) {
            sf0[r] = exp2hw(sf0[r]);
            sf1[r] = exp2hw(sf1[r]);
        }

        // lsum on the VALU pipe: 4-way ILP tree over this lane's 32 p's
        {
            float t0 = 0.f, t1 = 0.f, t2 = 0.f, t3 = 0.f;
            #pragma unroll
            for (int r = 0; r < 16; r += 4) {
                t0 += sf0[r];     t1 += sf0[r + 1];
                t2 += sf0[r + 2]; t3 += sf0[r + 3];
            }
            #pragma unroll
            for (int r = 0; r < 16; r += 4) {
                t0 += sf1[r];     t1 += sf1[r + 1];
                t2 += sf1[r + 2]; t3 += sf1[r + 3];
            }
            ls += (t0 + t1) + (t2 + t3);
        }

        // PV B-fragments: window ks = lane's own regs r0..r0+7 packed in order
        s8 pf[4];
        #pragma unroll
        for (int ks = 0; ks < 4; ++ks) {
            const f16v& pv = (ks < 2) ? sf0 : sf1;
            const int r0 = 8 * (ks & 1);
            union { u32 wd[4]; s8 v; } u;
            u.wd[0] = pkbf(pv[r0 + 0], pv[r0 + 1]);
            u.wd[1] = pkbf(pv[r0 + 2], pv[r0 + 3]);
            u.wd[2] = pkbf(pv[r0 + 4], pv[r0 + 5]);
            u.wd[3] = pkbf(pv[r0 + 6], pv[r0 + 7]);
            pf[ks] = u.v;
        }

        // O^T += V^T P
        __builtin_amdgcn_s_setprio(1);
        #pragma unroll
        for (int ks = 0; ks < 4; ++ks) {
            s8 vf0 = *(const s8*)(Vl + loff[ks]);
            s8 vf1 = *(const s8*)(Vl + loff[ks] + 2048);
            oacc0 = __builtin_amdgcn_mfma_f32_32x32x16_bf16(vf0, pf[ks], oacc0, 0, 0, 0);
            oacc1 = __builtin_amdgcn_mfma_f32_32x32x16_bf16(vf1, pf[ks], oacc1, 0, 0, 0);
        }
        __builtin_amdgcn_s_setprio(0);

        cur = (cur == 2) ? 0 : cur + 1;
    }

    // denominator: own 32-sum + partner half-lane's 32-sum
    const float inv = 1.0f / (ls + __shfl_xor(ls, 32));
    u16* orow = o + (qrow0 + l31) * kC + h * 64;
    #pragma unroll
    for (int db = 0; db < 2; ++db) {
        const f16v& oa = db ? oacc1 : oacc0;
        #pragma unroll
        for (int g = 0; g < 4; ++g) {
            int d0 = db * 32 + g * 8 + 4 * h5;
            u32 w0 = pkbf(oa[g * 4 + 0] * inv, oa[g * 4 + 1] * inv);
            u32 w1 = pkbf(oa[g * 4 + 2] * inv, oa[g * 4 + 3] * inv);
            u16x4 pk;
            pk[0] = (u16)(w0 & 0xffff); pk[1] = (u16)(w0 >> 16);
            pk[2] = (u16)(w1 & 0xffff); pk[3] = (u16)(w1 >> 16);
            *(u16x4*)&orow[d0] = pk;
        }
    }
}

// ---------------------------------------------------------------------------
extern "C" void kernel_launch(void* const* d_in, const int* in_sizes, int n_in,
                              void* d_out, int out_size, void* d_ws, size_t ws_size,
                              hipStream_t stream)
{
    const float* x      = (const float*)d_in[0];
    const float* gn_w   = (const float*)d_in[1];
    const float* gn_b   = (const float*)d_in[2];
    const float* conv_w = (const float*)d_in[3];
    const float* conv_b = (const float*)d_in[4];
    const float* wq     = (const float*)d_in[5];
    const float* bq     = (const float*)d_in[6];
    const float* wk     = (const float*)d_in[7];
    const float* bk     = (const float*)d_in[8];
    const float* wv     = (const float*)d_in[9];
    const float* bv     = (const float*)d_in[10];
    const float* wo     = (const float*)d_in[11];
    const float* bo     = (const float*)d_in[12];
    float* out = (float*)d_out;

    char* ws = (char*)d_ws;
    float2* stats = (float2*)ws;                       // 4 KB (8 KB reserved)
    u16* wqkvB  = (u16*)(ws + 8192);                   // 1.5 MB (q|k|v stacked)
    u16* woB    = wqkvB + 786432;                      // 0.5 MB (contiguous after wqkvB)
    u16* convwT = woB + 262144;                        // 0.5 MB
    u16* wqkvF  = convwT + 262144;                     // 1.5 MB (folded weights)
    float* bqkvF = (float*)(wqkvF + 786432);           // 6 KB
    const size_t ACT = (size_t)kB * kL * kC;
    u16* xt  = (u16*)(ws + (6 << 20));
    u16* qb  = xt + ACT;
    u16* kb  = qb + ACT;
    u16* vtb = kb + ACT;
    u16* res = xt;   // xt dead after QKV GEMM; reuse for attention output

    // --- fused prep: weight cvt + conv_w transpose + bias fold + GN stats ---
    prep1_kernel<<<1984, 256, 0, stream>>>(wq, wk, wv, wo, conv_w,
                                           bq, bk, bv, conv_b, x,
                                           wqkvB, convwT, bqkvF, stats);
    // W' = Wqkv @ conv_w   (fold 1x1 conv into QKV projections)
    gemm_mfma<3><<<dim3(4, 12, 1), 256, 0, stream>>>(
        wqkvB, convwT, nullptr, wqkvF, nullptr, nullptr, nullptr, nullptr);
    // GN-normalize + transpose input
    gn_t_kernel<<<dim3(16, 8, kB), 256, 0, stream>>>(x, stats, gn_w, gn_b, xt);

    // q,k,v (v transposed) from normalized input via folded weights (flat grid)
    gemm_mfma<1><<<1536, 256, 0, stream>>>(
        wqkvF, xt, bqkvF, qb, kb, vtb, nullptr, nullptr);
    attn_mfma<<<dim3(512), 512, 0, stream>>>(qb, kb, vtb, res);
    // out = wo @ res + bo + x  (flat grid)
    gemm_mfma<2><<<512, 256, 0, stream>>>(
        woB, res, bo, nullptr, nullptr, nullptr, x, out);
}